// Round 5
// baseline (12798.731 us; speedup 1.0000x reference)
//
#include <hip/hip_runtime.h>
#include <hip/hip_bf16.h>

#define H1 1024
#define FOURH 4096
#define BATCH 512
#define SEQ 64
#define DIN 128
#define TDEC 8
#define NWG 256

typedef float f32x4 __attribute__((ext_vector_type(4)));
typedef __bf16 bf16x8 __attribute__((ext_vector_type(8)));

// global->LDS direct, 16B per lane. LDS dest is wave-uniform base + lane*16.
__device__ __forceinline__ void gl_lds16(const void* g, void* l) {
    __builtin_amdgcn_global_load_lds(
        (const __attribute__((address_space(1))) unsigned int*)g,
        (__attribute__((address_space(3))) unsigned int*)l, 16, 0, 0);
}

// ---------------------------------------------------------------------------
// Persistent whole-network kernel. 256 blocks (1/CU, forced by 96KB LDS), 144
// {GEMM phase -> gridbar -> cell phase -> gridbar} rounds + head phase.
// GEMM phase: gates_partial = A0·B0^T + A1·B1^T, fp32 staged to LDS via
// global_load_lds (XOR-swizzled source), split to bf16 hi/lo in-register,
// 3-term MFMA. Tile 128x128xBK32, K-split 2 (ks half -> g0b/g1b).
// ---------------------------------------------------------------------------
__global__ __launch_bounds__(256) void lstm_persist(
    const float* __restrict__ x,
    const float* __restrict__ Wih0, const float* __restrict__ Whh0, const float* __restrict__ b0,
    const float* __restrict__ Wih1, const float* __restrict__ Whh1, const float* __restrict__ b1,
    const float* __restrict__ dWih, const float* __restrict__ dWhh, const float* __restrict__ db,
    const float* __restrict__ Wout, const float* __restrict__ bout,
    float* __restrict__ g0b, float* __restrict__ g1b,
    float* __restrict__ h0a, float* __restrict__ h0b, float* __restrict__ h1f,
    float* __restrict__ c0, float* __restrict__ c1,
    unsigned* __restrict__ bar, float* __restrict__ out)
{
    extern __shared__ char smem[];            // 3 * (16KB A + 16KB B)
    const int wg   = blockIdx.x;
    const int tid  = threadIdx.x;
    const int lane = tid & 63;
    const int w    = tid >> 6;                // wave 0..3
    const int wm   = w >> 1, wn = w & 1;
    const int bn   = wg & 31;                 // 32 col-tiles of 128
    const int bm   = (wg >> 5) & 3;           // 4 row-tiles of 128
    const int ks   = wg >> 7;                 // K-split half
    float* gout = ks ? g1b : g0b;

    unsigned bcount = 0;
    auto gridbar = [&]() {
        ++bcount;
        __syncthreads();
        if (tid == 0) {
            __threadfence();                  // release (agent scope)
            __hip_atomic_fetch_add(bar, 1u, __ATOMIC_RELAXED, __HIP_MEMORY_SCOPE_AGENT);
            const unsigned target = bcount * NWG;
            int spins = 0;
            while (__hip_atomic_load(bar, __ATOMIC_RELAXED, __HIP_MEMORY_SCOPE_AGENT) < target) {
                __builtin_amdgcn_s_sleep(2);
                if (++spins > (1 << 20)) break;   // bounded: fail visibly, never hang
            }
            __threadfence();                  // acquire
        }
        __syncthreads();
    };

    // ---- staging geometry (constant across phases) ----
    const int rsub = lane >> 3;               // row within 8-row stripe
    const int gsw  = (lane & 7) ^ rsub;       // swizzled source granule (16B)
    int rowj[4];
#pragma unroll
    for (int j = 0; j < 4; ++j) rowj[j] = (j * 4 + w) * 8 + rsub;

    int rA[4], rB[4];
#pragma unroll
    for (int f = 0; f < 4; ++f) {
        rA[f] = wm * 64 + f * 16 + (lane & 15);
        rB[f] = wn * 64 + f * 16 + (lane & 15);
    }
    const int hi4 = lane >> 4;
    const int g2  = hi4 * 2;

    const int kh1 = H1 / 2;                   // A1/B1 K-half, always 512

    for (int ph = 0; ph < 2 * (SEQ + TDEC); ++ph) {
        const int l = ph & 1, step = ph >> 1;
        float* hc = (step & 1) ? h0b : h0a;
        float* hn = (step & 1) ? h0a : h0b;
        const float *A0, *B0, *A1, *B1, *bias;
        float *cst, *hout;
        int lda0, kh0;
        if (step < SEQ) {
            if (l == 0) { A0 = x + (size_t)step * DIN; lda0 = SEQ * DIN; B0 = Wih0; kh0 = DIN / 2;
                          A1 = hc;  B1 = Whh0; bias = b0; cst = c0; hout = hn;  }
            else        { A0 = hn;  lda0 = H1; B0 = Wih1; kh0 = kh1;
                          A1 = h1f; B1 = Whh1; bias = b1; cst = c1; hout = h1f; }
        } else {
            if (l == 0) { A0 = h1f; lda0 = H1; B0 = dWih; kh0 = kh1;
                          A1 = hc;  B1 = dWhh; bias = db; cst = c0; hout = hn;  }
            else        { A0 = hn;  lda0 = H1; B0 = dWih + (size_t)FOURH * H1; kh0 = kh1;
                          A1 = h1f; B1 = dWhh + (size_t)FOURH * H1;
                          bias = db + FOURH; cst = c1; hout = h1f; }
        }
        const int ldb0 = kh0 * 2;             // weight row length == K
        const int n0 = kh0 >> 5, n1 = kh1 >> 5;
        const int n  = n0 + n1;
        const float* A0k = A0 + ks * kh0;
        const float* B0k = B0 + ks * kh0;
        const float* A1k = A1 + ks * kh1;
        const float* B1k = B1 + ks * kh1;

        auto stage = [&](int ii, int buf) {
            const float* A; const float* B; int lda, ldb, kk;
            if (ii < n0) { A = A0k; B = B0k; lda = lda0; ldb = ldb0; kk = ii << 5; }
            else         { A = A1k; B = B1k; lda = H1;   ldb = H1;   kk = (ii - n0) << 5; }
            const float* aU = A + (size_t)(bm * 128) * lda + kk;
            const float* bU = B + (size_t)(bn * 128) * ldb + kk;
            char* lA = smem + buf * 32768;
            char* lB = lA + 16384;
#pragma unroll
            for (int j = 0; j < 4; ++j) {
                gl_lds16(aU + (size_t)rowj[j] * lda + gsw * 4, lA + (j * 4 + w) * 1024);
                gl_lds16(bU + (size_t)rowj[j] * ldb + gsw * 4, lB + (j * 4 + w) * 1024);
            }
        };

        f32x4 acc[4][4];
#pragma unroll
        for (int mf = 0; mf < 4; ++mf)
#pragma unroll
            for (int nf = 0; nf < 4; ++nf)
                acc[mf][nf] = (f32x4){0.f, 0.f, 0.f, 0.f};

        stage(0, 0);
        stage(1, 1);

        int buf = 0;
        for (int i = 0; i < n; ++i) {
            if (i < n - 1) asm volatile("s_waitcnt vmcnt(8)" ::: "memory");
            else           asm volatile("s_waitcnt vmcnt(0)" ::: "memory");
            __builtin_amdgcn_sched_barrier(0);
            __builtin_amdgcn_s_barrier();
            __builtin_amdgcn_sched_barrier(0);

            if (i + 2 < n) {
                int b2 = buf + 2; if (b2 >= 3) b2 -= 3;
                stage(i + 2, b2);
            }

            char* lA = smem + buf * 32768;
            char* lB = lA + 16384;

            bf16x8 ah[4], al[4], bh[4], bl[4];
#pragma unroll
            for (int f = 0; f < 4; ++f) {
                {
                    int r = rA[f], s = r & 7;
                    f32x4 v0 = *(const f32x4*)(lA + r * 128 + ((g2    ) ^ s) * 16);
                    f32x4 v1 = *(const f32x4*)(lA + r * 128 + ((g2 + 1) ^ s) * 16);
#pragma unroll
                    for (int e = 0; e < 4; ++e) {
                        __bf16 h0 = (__bf16)v0[e];
                        ah[f][e] = h0; al[f][e] = (__bf16)(v0[e] - (float)h0);
                        __bf16 hh1 = (__bf16)v1[e];
                        ah[f][e + 4] = hh1; al[f][e + 4] = (__bf16)(v1[e] - (float)hh1);
                    }
                }
                {
                    int r = rB[f], s = r & 7;
                    f32x4 v0 = *(const f32x4*)(lB + r * 128 + ((g2    ) ^ s) * 16);
                    f32x4 v1 = *(const f32x4*)(lB + r * 128 + ((g2 + 1) ^ s) * 16);
#pragma unroll
                    for (int e = 0; e < 4; ++e) {
                        __bf16 h0 = (__bf16)v0[e];
                        bh[f][e] = h0; bl[f][e] = (__bf16)(v0[e] - (float)h0);
                        __bf16 hh1 = (__bf16)v1[e];
                        bh[f][e + 4] = hh1; bl[f][e + 4] = (__bf16)(v1[e] - (float)hh1);
                    }
                }
            }
#pragma unroll
            for (int mf = 0; mf < 4; ++mf)
#pragma unroll
                for (int nf = 0; nf < 4; ++nf) {
                    acc[mf][nf] = __builtin_amdgcn_mfma_f32_16x16x32_bf16(
                        ah[mf], bh[nf], acc[mf][nf], 0, 0, 0);
                    acc[mf][nf] = __builtin_amdgcn_mfma_f32_16x16x32_bf16(
                        ah[mf], bl[nf], acc[mf][nf], 0, 0, 0);
                    acc[mf][nf] = __builtin_amdgcn_mfma_f32_16x16x32_bf16(
                        al[mf], bh[nf], acc[mf][nf], 0, 0, 0);
                }
            __builtin_amdgcn_sched_barrier(0);
            buf = buf + 1; if (buf >= 3) buf -= 3;
        }

        // epilogue: C layout col=lane&15, row=(lane>>4)*4 + jj (m89-verified)
#pragma unroll
        for (int mf = 0; mf < 4; ++mf)
#pragma unroll
            for (int nf = 0; nf < 4; ++nf) {
                int row0 = bm * 128 + wm * 64 + mf * 16 + hi4 * 4;
                int col  = bn * 128 + wn * 64 + nf * 16 + (lane & 15);
#pragma unroll
                for (int jj = 0; jj < 4; ++jj)
                    gout[(size_t)(row0 + jj) * FOURH + col] = acc[mf][nf][jj];
            }

        gridbar();   // gates complete

        // ---- cell phase: this block's 1/256 slice of [512][1024] ----
#pragma unroll
        for (int r = 0; r < 2; ++r) {
            int q  = wg * 512 + r * 256 + tid;      // f32x4 index over 512*1024/4
            int b  = q >> 8;
            int u4 = q & 255;
            size_t base = (size_t)b * FOURH + u4 * 4;
            f32x4 gi = *(const f32x4*)(g0b + base)          + *(const f32x4*)(g1b + base)          + *(const f32x4*)(bias + u4 * 4);
            f32x4 gf = *(const f32x4*)(g0b + base + H1)     + *(const f32x4*)(g1b + base + H1)     + *(const f32x4*)(bias + H1 + u4 * 4);
            f32x4 gg = *(const f32x4*)(g0b + base + 2 * H1) + *(const f32x4*)(g1b + base + 2 * H1) + *(const f32x4*)(bias + 2 * H1 + u4 * 4);
            f32x4 go = *(const f32x4*)(g0b + base + 3 * H1) + *(const f32x4*)(g1b + base + 3 * H1) + *(const f32x4*)(bias + 3 * H1 + u4 * 4);
            size_t sidx = (size_t)b * H1 + u4 * 4;
            f32x4 cv = *(const f32x4*)(cst + sidx);
            f32x4 cn, hv;
#pragma unroll
            for (int e = 0; e < 4; ++e) {
                float si = 1.f / (1.f + expf(-gi[e]));
                float sf = 1.f / (1.f + expf(-gf[e]));
                float so = 1.f / (1.f + expf(-go[e]));
                float cc = sf * cv[e] + si * tanhf(gg[e]);
                cn[e] = cc;
                hv[e] = so * tanhf(cc);
            }
            *(f32x4*)(cst + sidx)  = cn;
            *(f32x4*)(hout + sidx) = hv;
        }

        gridbar();   // h/c visible for next phase
    }

    // ---- head phase: out[b][o] = h1·W_out[o] + b_out[o], duplicated ----
    {
        int idx = wg * 256 + tid;                  // 0..65535, need 8192
        if (idx < BATCH * 16) {
            int b = idx >> 4, o = idx & 15;
            const f32x4* hv = (const f32x4*)(h1f + (size_t)b * H1);
            const f32x4* wv = (const f32x4*)(Wout + (size_t)o * H1);
            float s = bout[o];
#pragma unroll 4
            for (int k = 0; k < H1 / 4; ++k) {
                f32x4 a = hv[k];
                f32x4 wq = wv[k];
                s += a[0] * wq[0] + a[1] * wq[1] + a[2] * wq[2] + a[3] * wq[3];
            }
            out[(size_t)b * 32 + o]      = s;
            out[(size_t)b * 32 + 16 + o] = s;
        }
    }
}

// ===========================================================================
extern "C" void kernel_launch(void* const* d_in, const int* in_sizes, int n_in,
                              void* d_out, int out_size, void* d_ws, size_t ws_size,
                              hipStream_t stream)
{
    const float* x    = (const float*)d_in[0];
    const float* Wih0 = (const float*)d_in[1];
    const float* Whh0 = (const float*)d_in[2];
    const float* b0   = (const float*)d_in[3];
    const float* Wih1 = (const float*)d_in[4];
    const float* Whh1 = (const float*)d_in[5];
    const float* b1   = (const float*)d_in[6];
    const float* dWih = (const float*)d_in[7];
    const float* dWhh = (const float*)d_in[8];
    const float* db   = (const float*)d_in[9];
    const float* Wout = (const float*)d_in[10];
    const float* bout = (const float*)d_in[11];

    float* ws  = (float*)d_ws;
    float* g0b = ws;                               // 512*4096
    float* g1b = g0b + (size_t)BATCH * FOURH;      // 512*4096
    float* h0a = g1b + (size_t)BATCH * FOURH;      // 5 x 512*1024 below
    float* h0b = h0a + (size_t)BATCH * H1;
    float* h1f = h0b + (size_t)BATCH * H1;
    float* c0  = h1f + (size_t)BATCH * H1;
    float* c1  = c0 + (size_t)BATCH * H1;
    unsigned* bar = (unsigned*)(c1 + (size_t)BATCH * H1);

    // zero h0a,h0b,h1,c0,c1 (contiguous) + barrier counter
    hipMemsetAsync(h0a, 0, 5 * (size_t)BATCH * H1 * sizeof(float), stream);
    hipMemsetAsync(bar, 0, 64, stream);

    hipFuncSetAttribute(reinterpret_cast<const void*>(lstm_persist),
                        hipFuncAttributeMaxDynamicSharedMemorySize, 98304);

    lstm_persist<<<dim3(NWG), dim3(256), 98304, stream>>>(
        x, Wih0, Whh0, b0, Wih1, Whh1, b1, dWih, dWhh, db, Wout, bout,
        g0b, g1b, h0a, h0b, h1f, c0, c1, bar, (float*)d_out);
}

// Round 7
// 6576.546 us; speedup vs baseline: 1.9461x; 1.9461x over previous
//
#include <hip/hip_runtime.h>
#include <hip/hip_bf16.h>

#define H1 1024
#define FOURH 4096
#define BATCH 512
#define SEQ 64
#define DIN 128
#define TDEC 8

typedef float f32x4 __attribute__((ext_vector_type(4)));
typedef __bf16 bf16x4 __attribute__((ext_vector_type(4)));
typedef __bf16 bf16x8 __attribute__((ext_vector_type(8)));

#define SCR_STRIDE 68            // f32 elems; 68*4 % 128 = 16 -> quarter-shifted banks
#define SCR_WBYTES (64 * SCR_STRIDE * 4)   // 17408 B per wave partial

// global->LDS direct, 16B per lane. LDS dest is wave-uniform base + lane*16.
__device__ __forceinline__ void gl_lds16(const void* g, void* l) {
    __builtin_amdgcn_global_load_lds(
        (const __attribute__((address_space(1))) unsigned int*)g,
        (__attribute__((address_space(3))) unsigned int*)l, 16, 0, 0);
}

// fp32 [R][K] -> bf16 pair [R][2K] (hi | lo).  K = 4<<k4shift elements.
__global__ __launch_bounds__(256) void conv_pair_k(
    const float* __restrict__ src, __bf16* __restrict__ dst,
    int total4, int k4shift)
{
    int i = blockIdx.x * 256 + threadIdx.x;
    if (i >= total4) return;
    int K4 = 1 << k4shift;
    int r  = i >> k4shift;
    int c4 = i & (K4 - 1);
    int K  = K4 * 4;
    f32x4 v = *(const f32x4*)(src + (size_t)r * K + c4 * 4);
    bf16x4 hi, lo;
#pragma unroll
    for (int e = 0; e < 4; ++e) {
        __bf16 h = (__bf16)v[e];
        hi[e] = h;
        lo[e] = (__bf16)(v[e] - (float)h);
    }
    __bf16* d = dst + (size_t)r * 2 * K;
    *(bf16x4*)(d + c4 * 4)     = hi;
    *(bf16x4*)(d + K + c4 * 4) = lo;
}

// ---------------------------------------------------------------------------
// Fused GEMM + LSTM cell, one dispatch per layer-step.
// Block = 128 batch x 16 units (64 gate-cols: col c -> unit c>>2, gate c&3).
// grid 256 = 4 bm x 64 uc. 512 threads = 8 waves = 2 m-groups x 4 k-groups;
// wave tile 64x64 (4x4 frags of 16x16x32 MFMA), 3-term bf16 hi/lo split.
// Wave (kg,mw) computes chunks i with (i&3)==kg; k-partials reduced in LDS.
// PAIR mode: operands pre-split bf16 [hi(K)|lo(K)] rows (4B/elem, same bytes
// as f32). !PAIR: operands fp32, split in-register after ds_read.
// Byte strides are IDENTICAL in both modes (pair row 2K*2B == f32 row K*4B).
// LDS: 6 chunk buffers x (A 16KB + B 8KB) = 144KB; 5-deep prefetch with
// counted vmcnt (3 global_load_lds per lane per stage).
// Weight row for gate-col c of unit chunk uc: (c&3)*1024 + uc*16 + (c>>2),
// so the cell epilogue reads (i,f,g,o) of one unit as one contiguous f32x4.
// ---------------------------------------------------------------------------
template<bool PAIR>
__global__ __launch_bounds__(512, 2) void lstm_fused(
    const void* __restrict__ a0v, long long arow_b, int k0,
    const void* __restrict__ w0v,
    const void* __restrict__ a1v,
    const void* __restrict__ w1v,
    const float* __restrict__ bias,
    float* __restrict__ cst, void* __restrict__ houtv)
{
    extern __shared__ char smem[];            // 6 * 24576 = 147456
    const int tid  = threadIdx.x;
    const int lane = tid & 63;
    const int w    = tid >> 6;                // wave 0..7
    const int kg   = w >> 1;                  // k-group 0..3
    const int mw   = w & 1;                   // m-group 0..1
    const int wg   = blockIdx.x;
    const int bm   = wg >> 6;                 // 0..3 (128-row batch tile)
    const int uc   = wg & 63;                 // 0..63 (16-unit chunk)

    const int nA = k0 >> 5;                   // chunks in input segment
    const int n  = nA + (H1 >> 5);            // + recurrent segment

    // ---- staging geometry ----
    const int rsub = lane >> 3;               // row within wave's 8-row stripe
    const int slot = lane & 7;                // dest granule slot
    const int gsw  = slot ^ rsub;             // source granule (XOR swizzle)
    const int brow = w * 8 + rsub;            // B tile row (= gate-col) 0..63
    const int wrow = (brow & 3) * H1 + uc * 16 + (brow >> 2);

    long long offA, off1;
    if constexpr (PAIR) {
        offA = (gsw < 4 ? gsw * 8 : k0 + (gsw - 4) * 8) * 2;
        off1 = (gsw < 4 ? gsw * 8 : H1 + (gsw - 4) * 8) * 2;
    } else {
        offA = gsw * 16;
        off1 = gsw * 16;
    }
    const int chunk_b = PAIR ? 64 : 128;      // hi-seg bytes per 32-elem chunk

    const char* pa0_0 = (const char*)a0v + (size_t)(bm * 128 + w * 8 + rsub) * arow_b + offA;
    const char* pa0_1 = pa0_0 + 64 * arow_b;
    const char* pw0   = (const char*)w0v + (size_t)wrow * (4 * (size_t)k0) + offA;
    const char* pa1_0 = (const char*)a1v + (size_t)(bm * 128 + w * 8 + rsub) * 4096 + off1;
    const char* pa1_1 = pa1_0 + 64 * 4096;
    const char* pw1   = (const char*)w1v + (size_t)wrow * 4096 + off1;

    auto stage = [&](int ii, int buf) {
        char* bufA = smem + buf * 24576;
        char* bufB = bufA + 16384;
        const char *s0, *s1, *sB;
        if (ii < nA) {
            size_t kb = (size_t)ii * chunk_b;
            s0 = pa0_0 + kb; s1 = pa0_1 + kb; sB = pw0 + kb;
        } else {
            size_t kb = (size_t)(ii - nA) * chunk_b;
            s0 = pa1_0 + kb; s1 = pa1_1 + kb; sB = pw1 + kb;
        }
        gl_lds16(s0, bufA + w * 1024);
        gl_lds16(s1, bufA + 8192 + w * 1024);
        gl_lds16(sB, bufB + w * 1024);
    };

    // ---- fragment geometry (16x16x32, wave tile 64x64) ----
    int rA[4], rB[4];
#pragma unroll
    for (int f = 0; f < 4; ++f) {
        rA[f] = mw * 64 + f * 16 + (lane & 15);   // batch row in 128-tile
        rB[f] = f * 16 + (lane & 15);             // gate-col in 64-tile
    }
    const int s7 = lane & 7;
    const int g0 = lane >> 4;                 // k-granule group 0..3

    f32x4 acc[4][4];
#pragma unroll
    for (int mf = 0; mf < 4; ++mf)
#pragma unroll
        for (int nf = 0; nf < 4; ++nf)
            acc[mf][nf] = (f32x4){0.f, 0.f, 0.f, 0.f};

    stage(0, 0); stage(1, 1); stage(2, 2); stage(3, 3); stage(4, 4);

    int buf = 0;
    for (int i = 0; i < n; ++i) {
        const int ahead = (i + 5 <= n) ? 4 : (n - i - 1);
        if (ahead == 4)      asm volatile("s_waitcnt vmcnt(12)" ::: "memory");
        else if (ahead == 3) asm volatile("s_waitcnt vmcnt(9)"  ::: "memory");
        else if (ahead == 2) asm volatile("s_waitcnt vmcnt(6)"  ::: "memory");
        else if (ahead == 1) asm volatile("s_waitcnt vmcnt(3)"  ::: "memory");
        else                 asm volatile("s_waitcnt vmcnt(0)"  ::: "memory");
        __builtin_amdgcn_sched_barrier(0);
        __builtin_amdgcn_s_barrier();
        __builtin_amdgcn_sched_barrier(0);

        if (i + 5 < n) stage(i + 5, (buf + 5 >= 6) ? buf - 1 : buf + 5);

        if ((i & 3) == kg) {                  // wave-uniform branch
            char* bufA = smem + buf * 24576;
            char* bufB = bufA + 16384;
            bf16x8 ah[4], al[4], bh[4], bl[4];
#pragma unroll
            for (int f = 0; f < 4; ++f) {
                if constexpr (PAIR) {
                    ah[f] = *(const bf16x8*)(bufA + rA[f] * 128 + ((g0    ) ^ s7) * 16);
                    al[f] = *(const bf16x8*)(bufA + rA[f] * 128 + ((g0 + 4) ^ s7) * 16);
                    bh[f] = *(const bf16x8*)(bufB + rB[f] * 128 + ((g0    ) ^ s7) * 16);
                    bl[f] = *(const bf16x8*)(bufB + rB[f] * 128 + ((g0 + 4) ^ s7) * 16);
                } else {
                    f32x4 v0 = *(const f32x4*)(bufA + rA[f] * 128 + ((2 * g0    ) ^ s7) * 16);
                    f32x4 v1 = *(const f32x4*)(bufA + rA[f] * 128 + ((2 * g0 + 1) ^ s7) * 16);
#pragma unroll
                    for (int e = 0; e < 4; ++e) {
                        __bf16 h0 = (__bf16)v0[e];
                        ah[f][e] = h0; al[f][e] = (__bf16)(v0[e] - (float)h0);
                        __bf16 h1 = (__bf16)v1[e];
                        ah[f][e + 4] = h1; al[f][e + 4] = (__bf16)(v1[e] - (float)h1);
                    }
                    f32x4 u0 = *(const f32x4*)(bufB + rB[f] * 128 + ((2 * g0    ) ^ s7) * 16);
                    f32x4 u1 = *(const f32x4*)(bufB + rB[f] * 128 + ((2 * g0 + 1) ^ s7) * 16);
#pragma unroll
                    for (int e = 0; e < 4; ++e) {
                        __bf16 h0 = (__bf16)u0[e];
                        bh[f][e] = h0; bl[f][e] = (__bf16)(u0[e] - (float)h0);
                        __bf16 h1 = (__bf16)u1[e];
                        bh[f][e + 4] = h1; bl[f][e + 4] = (__bf16)(u1[e] - (float)h1);
                    }
                }
            }
#pragma unroll
            for (int mf = 0; mf < 4; ++mf)
#pragma unroll
                for (int nf = 0; nf < 4; ++nf) {
                    acc[mf][nf] = __builtin_amdgcn_mfma_f32_16x16x32_bf16(
                        ah[mf], bh[nf], acc[mf][nf], 0, 0, 0);
                    acc[mf][nf] = __builtin_amdgcn_mfma_f32_16x16x32_bf16(
                        ah[mf], bl[nf], acc[mf][nf], 0, 0, 0);
                    acc[mf][nf] = __builtin_amdgcn_mfma_f32_16x16x32_bf16(
                        al[mf], bh[nf], acc[mf][nf], 0, 0, 0);
                }
        }
        __builtin_amdgcn_sched_barrier(0);
        buf = (buf + 1 >= 6) ? 0 : buf + 1;
    }

    // ---- k-split reduce via LDS + fused cell ----
    __syncthreads();                          // all chunk reads complete
    {
        float* scr = (float*)(smem + w * SCR_WBYTES);
        const int q4 = lane >> 4;
#pragma unroll
        for (int mf = 0; mf < 4; ++mf)
#pragma unroll
            for (int nf = 0; nf < 4; ++nf) {
                int cl = nf * 16 + (lane & 15);
#pragma unroll
                for (int j = 0; j < 4; ++j) {
                    int rl = mf * 16 + q4 * 4 + j;   // C layout m89-verified
                    scr[rl * SCR_STRIDE + cl] = acc[mf][nf][j];
                }
            }
    }
    __syncthreads();

#pragma unroll
    for (int p = 0; p < 4; ++p) {
        int id  = p * 512 + tid;              // 2048 cell items
        int u   = id & 15;
        int r   = (id >> 4) & 63;
        int mwi = id >> 10;
        f32x4 sum4 = (f32x4){0.f, 0.f, 0.f, 0.f};
#pragma unroll
        for (int kgi = 0; kgi < 4; ++kgi)
            sum4 += *(const f32x4*)(smem + (kgi * 2 + mwi) * SCR_WBYTES
                                    + (r * SCR_STRIDE + u * 4) * 4);
        int gu = uc * 16 + u;
        float gi = sum4[0] + bias[gu];
        float gf = sum4[1] + bias[H1 + gu];
        float gg = sum4[2] + bias[2 * H1 + gu];
        float go = sum4[3] + bias[3 * H1 + gu];
        float si = 1.f / (1.f + expf(-gi));
        float sf = 1.f / (1.f + expf(-gf));
        float so = 1.f / (1.f + expf(-go));
        int row_g = bm * 128 + mwi * 64 + r;
        size_t ci = (size_t)row_g * H1 + gu;
        float cc = sf * cst[ci] + si * tanhf(gg);
        cst[ci] = cc;
        float hv = so * tanhf(cc);
        if constexpr (PAIR) {
            __bf16* hp = (__bf16*)houtv;
            __bf16 hh = (__bf16)hv;
            hp[(size_t)row_g * 2048 + gu]        = hh;
            hp[(size_t)row_g * 2048 + 1024 + gu] = (__bf16)(hv - (float)hh);
        } else {
            ((float*)houtv)[(size_t)row_g * H1 + gu] = hv;
        }
    }
}

// head (pair h): out[b][o] = (h_hi+h_lo)·W_out[o] + b_out[o], duplicated +16.
__global__ __launch_bounds__(256) void head2_k(
    const __bf16* __restrict__ hp, const float* __restrict__ W,
    const float* __restrict__ bo, float* __restrict__ out)
{
    int idx = blockIdx.x * 256 + threadIdx.x;
    int b = idx >> 4, o = idx & 15;
    const __bf16* hr = hp + (size_t)b * 2048;
    const f32x4* wv = (const f32x4*)(W + (size_t)o * H1);
    float s = bo[o];
#pragma unroll 4
    for (int k4 = 0; k4 < 128; ++k4) {
        bf16x8 vh = *(const bf16x8*)(hr + k4 * 8);
        bf16x8 vl = *(const bf16x8*)(hr + 1024 + k4 * 8);
        f32x4 w0 = wv[k4 * 2], w1 = wv[k4 * 2 + 1];
#pragma unroll
        for (int e = 0; e < 4; ++e)
            s += ((float)vh[e] + (float)vl[e]) * w0[e];
#pragma unroll
        for (int e = 4; e < 8; ++e)
            s += ((float)vh[e] + (float)vl[e]) * w1[e - 4];
    }
    out[(size_t)b * 32 + o]      = s;
    out[(size_t)b * 32 + 16 + o] = s;
}

// head (f32 h)
__global__ __launch_bounds__(256) void head_k(
    const float* __restrict__ h, const float* __restrict__ W,
    const float* __restrict__ bo, float* __restrict__ out)
{
    int idx = blockIdx.x * 256 + threadIdx.x;
    int b = idx >> 4, o = idx & 15;
    const f32x4* hv = (const f32x4*)(h + (size_t)b * H1);
    const f32x4* wv = (const f32x4*)(W + (size_t)o * H1);
    float s = bo[o];
#pragma unroll 4
    for (int k = 0; k < H1 / 4; ++k) {
        f32x4 a = hv[k];
        f32x4 wq = wv[k];
        s += a[0] * wq[0] + a[1] * wq[1] + a[2] * wq[2] + a[3] * wq[3];
    }
    out[(size_t)b * 32 + o]      = s;
    out[(size_t)b * 32 + 16 + o] = s;
}

// ===========================================================================
extern "C" void kernel_launch(void* const* d_in, const int* in_sizes, int n_in,
                              void* d_out, int out_size, void* d_ws, size_t ws_size,
                              hipStream_t stream)
{
    const float* x    = (const float*)d_in[0];
    const float* Wih0 = (const float*)d_in[1];
    const float* Whh0 = (const float*)d_in[2];
    const float* b0   = (const float*)d_in[3];
    const float* Wih1 = (const float*)d_in[4];
    const float* Whh1 = (const float*)d_in[5];
    const float* b1   = (const float*)d_in[6];
    const float* dWih = (const float*)d_in[7];
    const float* dWhh = (const float*)d_in[8];
    const float* db   = (const float*)d_in[9];
    const float* Wout = (const float*)d_in[10];
    const float* bout = (const float*)d_in[11];

    dim3 blk(256);
    dim3 fgrid(256);
    dim3 fblk(512);

    const size_t W0SZ = (size_t)4096 * 256;        // Wih0 pair elems
    const size_t WBSZ = (size_t)4096 * 2048;       // big weight pair elems
    const size_t XPSZ = (size_t)BATCH * SEQ * 256; // x pair elems
    const size_t HPSZ = (size_t)BATCH * 2048;      // h pair elems
    const size_t CSZ  = (size_t)BATCH * H1;        // c / f32-h elems
    const size_t NEED = (W0SZ + 7 * WBSZ + XPSZ) * 2 + 4 * HPSZ * 2 + 2 * CSZ * 4;

    if (ws_size >= NEED) {
        // ---------------- pair mode ----------------
        __bf16* Wih0p  = (__bf16*)d_ws;
        __bf16* Whh0p  = Wih0p + W0SZ;
        __bf16* Wih1p  = Whh0p + WBSZ;
        __bf16* Whh1p  = Wih1p + WBSZ;
        __bf16* dWih0p = Whh1p + WBSZ;
        __bf16* dWhh0p = dWih0p + WBSZ;
        __bf16* dWih1p = dWhh0p + WBSZ;
        __bf16* dWhh1p = dWih1p + WBSZ;
        __bf16* xp     = dWhh1p + WBSZ;
        __bf16* hp0a   = xp + XPSZ;
        __bf16* hp0b   = hp0a + HPSZ;
        __bf16* hp1a   = hp0b + HPSZ;
        __bf16* hp1b   = hp1a + HPSZ;
        float*  c0     = (float*)(hp1b + HPSZ);
        float*  c1     = c0 + CSZ;

        auto conv = [&](const float* s, __bf16* d, int R, int shift) {
            int total4 = R * (1 << shift);
            conv_pair_k<<<(total4 + 255) / 256, blk, 0, stream>>>(s, d, total4, shift);
        };
        conv(Wih0, Wih0p, 4096, 5);
        conv(Whh0, Whh0p, 4096, 8);
        conv(Wih1, Wih1p, 4096, 8);
        conv(Whh1, Whh1p, 4096, 8);
        conv(dWih,                       dWih0p, 4096, 8);
        conv(dWih + (size_t)4096 * 1024, dWih1p, 4096, 8);
        conv(dWhh,                       dWhh0p, 4096, 8);
        conv(dWhh + (size_t)4096 * 1024, dWhh1p, 4096, 8);
        conv(x, xp, BATCH * SEQ, 5);

        // zero h pairs (4 x 2MB) + c (2 x 2MB), contiguous
        hipMemsetAsync(hp0a, 0, 4 * HPSZ * 2 + 2 * CSZ * 4, stream);

        (void)hipFuncSetAttribute(reinterpret_cast<const void*>(&lstm_fused<true>),
                                  hipFuncAttributeMaxDynamicSharedMemorySize, 147456);

        __bf16 *hc = hp0a, *hn = hp0b, *h1c = hp1a, *h1n = hp1b;
        for (int t = 0; t < SEQ; ++t) {
            lstm_fused<true><<<fgrid, fblk, 147456, stream>>>(
                xp + t * 256, (long long)(SEQ * 256 * 2), DIN, Wih0p,
                hc, Whh0p, b0, c0, hn);
            lstm_fused<true><<<fgrid, fblk, 147456, stream>>>(
                hn, 4096LL, H1, Wih1p, h1c, Whh1p, b1, c1, h1n);
            __bf16* t0 = hc; hc = hn; hn = t0;
            __bf16* t1 = h1c; h1c = h1n; h1n = t1;
        }
        for (int s = 0; s < TDEC; ++s) {
            lstm_fused<true><<<fgrid, fblk, 147456, stream>>>(
                h1c, 4096LL, H1, dWih0p, hc, dWhh0p, db, c0, hn);
            lstm_fused<true><<<fgrid, fblk, 147456, stream>>>(
                hn, 4096LL, H1, dWih1p, h1c, dWhh1p, db + FOURH, c1, h1n);
            __bf16* t0 = hc; hc = hn; hn = t0;
            __bf16* t1 = h1c; h1c = h1n; h1n = t1;
        }
        head2_k<<<dim3(32), blk, 0, stream>>>(h1c, Wout, bout, (float*)d_out);
    } else {
        // ---------------- f32 mode (in-register split, ~12MB ws) ----------------
        float* h0a = (float*)d_ws;
        float* h0b = h0a + CSZ;
        float* h1a = h0b + CSZ;
        float* h1b = h1a + CSZ;
        float* c0  = h1b + CSZ;
        float* c1  = c0 + CSZ;

        hipMemsetAsync(h0a, 0, 6 * CSZ * 4, stream);

        (void)hipFuncSetAttribute(reinterpret_cast<const void*>(&lstm_fused<false>),
                                  hipFuncAttributeMaxDynamicSharedMemorySize, 147456);

        const float* dWih1 = dWih + (size_t)FOURH * H1;
        const float* dWhh1 = dWhh + (size_t)FOURH * H1;

        float *hc = h0a, *hn = h0b, *h1c = h1a, *h1n = h1b;
        for (int t = 0; t < SEQ; ++t) {
            lstm_fused<false><<<fgrid, fblk, 147456, stream>>>(
                x + (size_t)t * DIN, (long long)(SEQ * DIN * 4), DIN, Wih0,
                hc, Whh0, b0, c0, hn);
            lstm_fused<false><<<fgrid, fblk, 147456, stream>>>(
                hn, 4096LL, H1, Wih1, h1c, Whh1, b1, c1, h1n);
            float* t0 = hc; hc = hn; hn = t0;
            float* t1 = h1c; h1c = h1n; h1n = t1;
        }
        for (int s = 0; s < TDEC; ++s) {
            lstm_fused<false><<<fgrid, fblk, 147456, stream>>>(
                h1c, 4096LL, H1, dWih, hc, dWhh, db, c0, hn);
            lstm_fused<false><<<fgrid, fblk, 147456, stream>>>(
                hn, 4096LL, H1, dWih1, h1c, dWhh1, db + FOURH, c1, h1n);
            float* t0 = hc; hc = hn; hn = t0;
            float* t1 = h1c; h1c = h1n; h1n = t1;
        }
        head_k<<<dim3(32), blk, 0, stream>>>(h1c, Wout, bout, (float*)d_out);
    }
}

// Round 8
// 5205.796 us; speedup vs baseline: 2.4586x; 1.2633x over previous
//
#include <hip/hip_runtime.h>
#include <hip/hip_bf16.h>

#define H1 1024
#define FOURH 4096
#define BATCH 512
#define SEQ 64
#define DIN 128
#define TDEC 8

typedef float f32x4 __attribute__((ext_vector_type(4)));
typedef __bf16 bf16x4 __attribute__((ext_vector_type(4)));
typedef __bf16 bf16x8 __attribute__((ext_vector_type(8)));

// global->LDS direct, 16B per lane. LDS dest is wave-uniform base + lane*16.
__device__ __forceinline__ void gl_lds16(const void* g, void* l) {
    __builtin_amdgcn_global_load_lds(
        (const __attribute__((address_space(1))) unsigned int*)g,
        (__attribute__((address_space(3))) unsigned int*)l, 16, 0, 0);
}

// fp32 [R][K] -> bf16 pair [R][2K] (hi | lo), rows unpermuted (for x).
__global__ __launch_bounds__(256) void conv_pair_k(
    const float* __restrict__ src, __bf16* __restrict__ dst,
    int total4, int k4shift)
{
    int i = blockIdx.x * 256 + threadIdx.x;
    if (i >= total4) return;
    int K4 = 1 << k4shift;
    int r  = i >> k4shift;
    int c4 = i & (K4 - 1);
    int K  = K4 * 4;
    f32x4 v = *(const f32x4*)(src + (size_t)r * K + c4 * 4);
    bf16x4 hi, lo;
#pragma unroll
    for (int e = 0; e < 4; ++e) {
        __bf16 h = (__bf16)v[e];
        hi[e] = h;
        lo[e] = (__bf16)(v[e] - (float)h);
    }
    __bf16* d = dst + (size_t)r * 2 * K;
    *(bf16x4*)(d + c4 * 4)     = hi;
    *(bf16x4*)(d + K + c4 * 4) = lo;
}

// weights [4096][K] -> pair rows PERMUTED: src row r (gate g=r>>10, unit
// u=r&1023) -> dst row (u>>5)*128 + (u&31)*4 + g, so a uc-block's 128
// gate-cols are contiguous and cell reads (i,f,g,o) as one f32x4.
__global__ __launch_bounds__(256) void conv_pair_perm_k(
    const float* __restrict__ src, __bf16* __restrict__ dst,
    int total4, int k4shift)
{
    int i = blockIdx.x * 256 + threadIdx.x;
    if (i >= total4) return;
    int K4 = 1 << k4shift;
    int r  = i >> k4shift;
    int c4 = i & (K4 - 1);
    int K  = K4 * 4;
    f32x4 v = *(const f32x4*)(src + (size_t)r * K + c4 * 4);
    bf16x4 hi, lo;
#pragma unroll
    for (int e = 0; e < 4; ++e) {
        __bf16 h = (__bf16)v[e];
        hi[e] = h;
        lo[e] = (__bf16)(v[e] - (float)h);
    }
    int g = r >> 10, u = r & 1023;
    int dr = (u >> 5) * 128 + (u & 31) * 4 + g;
    __bf16* d = dst + (size_t)dr * 2 * K;
    *(bf16x4*)(d + c4 * 4)     = hi;
    *(bf16x4*)(d + K + c4 * 4) = lo;
}

// ---------------------------------------------------------------------------
// Fused GEMM + LSTM cell. Block = 64 batch x 128 gate-cols (32 units, all 4
// gates; col c -> unit c>>2, gate c&3). grid 256 = 8 bm x 32 uc. 4 waves of
// 32x64 (2x4 frags 16x16x32), EVERY wave computes EVERY chunk (r4 geometry).
// 3-term bf16 hi/lo split; PAIR: operands pre-split (weights row-permuted),
// !PAIR: fp32 operands, in-register split, in-kernel row permutation.
// LDS: 3 buffers x (A 8KB + B 16KB) = 72KB; 2-deep prefetch, vmcnt(6).
// Epilogue: acc -> 32KB LDS scratch -> in-block cell (gates never hit HBM).
// ---------------------------------------------------------------------------
template<bool PAIR>
__global__ __launch_bounds__(256, 1) void lstm_fused(
    const void* __restrict__ a0v, long long arow_b, int k0,
    const void* __restrict__ w0v,
    const void* __restrict__ a1v,
    const void* __restrict__ w1v,
    const float* __restrict__ bias,
    float* __restrict__ cst, void* __restrict__ houtv)
{
    extern __shared__ char smem[];            // 3 * 24576 = 73728
    const int tid  = threadIdx.x;
    const int lane = tid & 63;
    const int w    = tid >> 6;                // wave 0..3
    const int wm   = w >> 1, wn = w & 1;      // 2m x 2n -> wave tile 32x64
    const int wg   = blockIdx.x;
    const int bm   = wg >> 5;                 // 0..7 (64-row batch tile)
    const int uc   = wg & 31;                 // 0..31 (32-unit chunk)

    const int nA = k0 >> 5;
    const int n  = nA + (H1 >> 5);

    // ---- staging geometry: 6 gl_lds16 per wave per chunk (A 2 + B 4) ----
    const int rsub = lane >> 3;
    const int slot = lane & 7;
    const int gsw  = slot ^ rsub;             // XOR-swizzled source granule

    long long offA0, offA1, offB0, offB1;
    if constexpr (PAIR) {
        offA0 = (long long)(gsw < 4 ? gsw * 8 : k0 + (gsw - 4) * 8) * 2;
        offA1 = (long long)(gsw < 4 ? gsw * 8 : H1 + (gsw - 4) * 8) * 2;
        offB0 = offA0; offB1 = offA1;
    } else {
        offA0 = offA1 = offB0 = offB1 = gsw * 16;
    }
    const int chunk_b = PAIR ? 64 : 128;      // hi-seg bytes per 32-elem chunk

    const char* paj0[2]; const char* paj1[2];
    const char* pbj0[4]; const char* pbj1[4];
#pragma unroll
    for (int j = 0; j < 2; ++j) {
        int ar = bm * 64 + w * 16 + j * 8 + rsub;
        paj0[j] = (const char*)a0v + (size_t)ar * arow_b + offA0;
        paj1[j] = (const char*)a1v + (size_t)ar * 4096 + offA1;
    }
#pragma unroll
    for (int j = 0; j < 4; ++j) {
        int c = w * 32 + j * 8 + rsub;        // gate-col 0..127
        int br0 = PAIR ? uc * 128 + c : (c & 3) * H1 + uc * 32 + (c >> 2);
        int br1 = br0;
        pbj0[j] = (const char*)w0v + (size_t)br0 * (4 * (size_t)k0) + offB0;
        pbj1[j] = (const char*)w1v + (size_t)br1 * 4096 + offB1;
    }

    auto stage = [&](int ii, int buf) {
        char* bufA = smem + buf * 24576;
        char* bufB = bufA + 8192;
        if (ii < nA) {
            size_t kb = (size_t)ii * chunk_b;
            gl_lds16(paj0[0] + kb, bufA + (w * 2    ) * 1024);
            gl_lds16(paj0[1] + kb, bufA + (w * 2 + 1) * 1024);
#pragma unroll
            for (int j = 0; j < 4; ++j)
                gl_lds16(pbj0[j] + kb, bufB + (w * 4 + j) * 1024);
        } else {
            size_t kb = (size_t)(ii - nA) * chunk_b;
            gl_lds16(paj1[0] + kb, bufA + (w * 2    ) * 1024);
            gl_lds16(paj1[1] + kb, bufA + (w * 2 + 1) * 1024);
#pragma unroll
            for (int j = 0; j < 4; ++j)
                gl_lds16(pbj1[j] + kb, bufB + (w * 4 + j) * 1024);
        }
    };

    // ---- fragment geometry ----
    int rA[2], rB[4];
#pragma unroll
    for (int f = 0; f < 2; ++f) rA[f] = wm * 32 + f * 16 + (lane & 15);
#pragma unroll
    for (int f = 0; f < 4; ++f) rB[f] = wn * 64 + f * 16 + (lane & 15);
    const int s7 = lane & 7;
    const int g0 = lane >> 4;                 // k-granule group 0..3

    f32x4 acc[2][4];
#pragma unroll
    for (int mf = 0; mf < 2; ++mf)
#pragma unroll
        for (int nf = 0; nf < 4; ++nf)
            acc[mf][nf] = (f32x4){0.f, 0.f, 0.f, 0.f};

    stage(0, 0);
    stage(1, 1);

    int buf = 0;
    for (int i = 0; i < n; ++i) {
        if (i < n - 1) asm volatile("s_waitcnt vmcnt(6)" ::: "memory");
        else           asm volatile("s_waitcnt vmcnt(0)" ::: "memory");
        __builtin_amdgcn_sched_barrier(0);
        __builtin_amdgcn_s_barrier();
        __builtin_amdgcn_sched_barrier(0);

        if (i + 2 < n) {
            int b2 = buf + 2; if (b2 >= 3) b2 -= 3;
            stage(i + 2, b2);
        }

        char* bufA = smem + buf * 24576;
        char* bufB = bufA + 8192;

        bf16x8 ah[2], al[2], bh[4], bl[4];
#pragma unroll
        for (int f = 0; f < 2; ++f) {
            if constexpr (PAIR) {
                ah[f] = *(const bf16x8*)(bufA + rA[f] * 128 + ((g0    ) ^ s7) * 16);
                al[f] = *(const bf16x8*)(bufA + rA[f] * 128 + ((g0 + 4) ^ s7) * 16);
            } else {
                f32x4 v0 = *(const f32x4*)(bufA + rA[f] * 128 + ((2 * g0    ) ^ s7) * 16);
                f32x4 v1 = *(const f32x4*)(bufA + rA[f] * 128 + ((2 * g0 + 1) ^ s7) * 16);
#pragma unroll
                for (int e = 0; e < 4; ++e) {
                    __bf16 h0 = (__bf16)v0[e];
                    ah[f][e] = h0; al[f][e] = (__bf16)(v0[e] - (float)h0);
                    __bf16 h1 = (__bf16)v1[e];
                    ah[f][e + 4] = h1; al[f][e + 4] = (__bf16)(v1[e] - (float)h1);
                }
            }
        }
#pragma unroll
        for (int f = 0; f < 4; ++f) {
            if constexpr (PAIR) {
                bh[f] = *(const bf16x8*)(bufB + rB[f] * 128 + ((g0    ) ^ s7) * 16);
                bl[f] = *(const bf16x8*)(bufB + rB[f] * 128 + ((g0 + 4) ^ s7) * 16);
            } else {
                f32x4 u0 = *(const f32x4*)(bufB + rB[f] * 128 + ((2 * g0    ) ^ s7) * 16);
                f32x4 u1 = *(const f32x4*)(bufB + rB[f] * 128 + ((2 * g0 + 1) ^ s7) * 16);
#pragma unroll
                for (int e = 0; e < 4; ++e) {
                    __bf16 h0 = (__bf16)u0[e];
                    bh[f][e] = h0; bl[f][e] = (__bf16)(u0[e] - (float)h0);
                    __bf16 h1 = (__bf16)u1[e];
                    bh[f][e + 4] = h1; bl[f][e + 4] = (__bf16)(u1[e] - (float)h1);
                }
            }
        }
#pragma unroll
        for (int mf = 0; mf < 2; ++mf)
#pragma unroll
            for (int nf = 0; nf < 4; ++nf) {
                acc[mf][nf] = __builtin_amdgcn_mfma_f32_16x16x32_bf16(
                    ah[mf], bh[nf], acc[mf][nf], 0, 0, 0);
                acc[mf][nf] = __builtin_amdgcn_mfma_f32_16x16x32_bf16(
                    ah[mf], bl[nf], acc[mf][nf], 0, 0, 0);
                acc[mf][nf] = __builtin_amdgcn_mfma_f32_16x16x32_bf16(
                    al[mf], bh[nf], acc[mf][nf], 0, 0, 0);
            }
        __builtin_amdgcn_sched_barrier(0);
        buf = buf + 1; if (buf >= 3) buf -= 3;
    }

    // ---- epilogue: acc -> LDS scratch [64][128] f32 ----
    __syncthreads();
    float* scr = (float*)smem;
#pragma unroll
    for (int mf = 0; mf < 2; ++mf)
#pragma unroll
        for (int nf = 0; nf < 4; ++nf) {
            int row0 = wm * 32 + mf * 16 + (lane >> 4) * 4;   // m89 C layout
            int col  = wn * 64 + nf * 16 + (lane & 15);
#pragma unroll
            for (int j = 0; j < 4; ++j)
                scr[(row0 + j) * 128 + col] = acc[mf][nf][j];
        }
    __syncthreads();

    // ---- in-block LSTM cell: 64 rows x 32 units = 2048 items ----
#pragma unroll
    for (int p = 0; p < 8; ++p) {
        int item = p * 256 + tid;
        int u = item & 31;                    // unit within block
        int r = item >> 5;                    // batch row within block
        f32x4 g4 = *(const f32x4*)(scr + r * 128 + u * 4);
        int gu = uc * 32 + u;                 // global unit 0..1023
        float gi = g4[0] + bias[gu];
        float gf = g4[1] + bias[H1 + gu];
        float gg = g4[2] + bias[2 * H1 + gu];
        float go = g4[3] + bias[3 * H1 + gu];
        float si = 1.f / (1.f + expf(-gi));
        float sf = 1.f / (1.f + expf(-gf));
        float so = 1.f / (1.f + expf(-go));
        int row_g = bm * 64 + r;
        size_t ci = (size_t)row_g * H1 + gu;
        float cc = sf * cst[ci] + si * tanhf(gg);
        cst[ci] = cc;
        float hv = so * tanhf(cc);
        if constexpr (PAIR) {
            __bf16* hp = (__bf16*)houtv;
            __bf16 hh = (__bf16)hv;
            hp[(size_t)row_g * 2048 + gu]        = hh;
            hp[(size_t)row_g * 2048 + 1024 + gu] = (__bf16)(hv - (float)hh);
        } else {
            ((float*)houtv)[(size_t)row_g * H1 + gu] = hv;
        }
    }
}

// head (pair h)
__global__ __launch_bounds__(256) void head2_k(
    const __bf16* __restrict__ hp, const float* __restrict__ W,
    const float* __restrict__ bo, float* __restrict__ out)
{
    int idx = blockIdx.x * 256 + threadIdx.x;
    int b = idx >> 4, o = idx & 15;
    const __bf16* hr = hp + (size_t)b * 2048;
    const f32x4* wv = (const f32x4*)(W + (size_t)o * H1);
    float s = bo[o];
#pragma unroll 4
    for (int k4 = 0; k4 < 128; ++k4) {
        bf16x8 vh = *(const bf16x8*)(hr + k4 * 8);
        bf16x8 vl = *(const bf16x8*)(hr + 1024 + k4 * 8);
        f32x4 w0 = wv[k4 * 2], w1 = wv[k4 * 2 + 1];
#pragma unroll
        for (int e = 0; e < 4; ++e)
            s += ((float)vh[e] + (float)vl[e]) * w0[e];
#pragma unroll
        for (int e = 4; e < 8; ++e)
            s += ((float)vh[e] + (float)vl[e]) * w1[e - 4];
    }
    out[(size_t)b * 32 + o]      = s;
    out[(size_t)b * 32 + 16 + o] = s;
}

// head (f32 h)
__global__ __launch_bounds__(256) void head_k(
    const float* __restrict__ h, const float* __restrict__ W,
    const float* __restrict__ bo, float* __restrict__ out)
{
    int idx = blockIdx.x * 256 + threadIdx.x;
    int b = idx >> 4, o = idx & 15;
    const f32x4* hv = (const f32x4*)(h + (size_t)b * H1);
    const f32x4* wv = (const f32x4*)(W + (size_t)o * H1);
    float s = bo[o];
#pragma unroll 4
    for (int k = 0; k < H1 / 4; ++k) {
        f32x4 a = hv[k];
        f32x4 wq = wv[k];
        s += a[0] * wq[0] + a[1] * wq[1] + a[2] * wq[2] + a[3] * wq[3];
    }
    out[(size_t)b * 32 + o]      = s;
    out[(size_t)b * 32 + 16 + o] = s;
}

// ===========================================================================
extern "C" void kernel_launch(void* const* d_in, const int* in_sizes, int n_in,
                              void* d_out, int out_size, void* d_ws, size_t ws_size,
                              hipStream_t stream)
{
    const float* x    = (const float*)d_in[0];
    const float* Wih0 = (const float*)d_in[1];
    const float* Whh0 = (const float*)d_in[2];
    const float* b0   = (const float*)d_in[3];
    const float* Wih1 = (const float*)d_in[4];
    const float* Whh1 = (const float*)d_in[5];
    const float* b1   = (const float*)d_in[6];
    const float* dWih = (const float*)d_in[7];
    const float* dWhh = (const float*)d_in[8];
    const float* db   = (const float*)d_in[9];
    const float* Wout = (const float*)d_in[10];
    const float* bout = (const float*)d_in[11];

    dim3 blk(256);
    dim3 fgrid(256);
    const size_t SMEM = 73728;

    const size_t W0SZ = (size_t)4096 * 256;
    const size_t WBSZ = (size_t)4096 * 2048;
    const size_t XPSZ = (size_t)BATCH * SEQ * 256;
    const size_t HPSZ = (size_t)BATCH * 2048;
    const size_t CSZ  = (size_t)BATCH * H1;
    const size_t NEED = (W0SZ + 7 * WBSZ + XPSZ) * 2 + 4 * HPSZ * 2 + 2 * CSZ * 4;

    if (ws_size >= NEED) {
        // ---------------- pair mode ----------------
        __bf16* Wih0p  = (__bf16*)d_ws;
        __bf16* Whh0p  = Wih0p + W0SZ;
        __bf16* Wih1p  = Whh0p + WBSZ;
        __bf16* Whh1p  = Wih1p + WBSZ;
        __bf16* dWih0p = Whh1p + WBSZ;
        __bf16* dWhh0p = dWih0p + WBSZ;
        __bf16* dWih1p = dWhh0p + WBSZ;
        __bf16* dWhh1p = dWih1p + WBSZ;
        __bf16* xp     = dWhh1p + WBSZ;
        __bf16* hp0a   = xp + XPSZ;
        __bf16* hp0b   = hp0a + HPSZ;
        __bf16* hp1a   = hp0b + HPSZ;
        __bf16* hp1b   = hp1a + HPSZ;
        float*  c0     = (float*)(hp1b + HPSZ);
        float*  c1     = c0 + CSZ;

        auto convp = [&](const float* s, __bf16* d, int shift) {
            int total4 = 4096 * (1 << shift);
            conv_pair_perm_k<<<(total4 + 255) / 256, blk, 0, stream>>>(s, d, total4, shift);
        };
        convp(Wih0, Wih0p, 5);
        convp(Whh0, Whh0p, 8);
        convp(Wih1, Wih1p, 8);
        convp(Whh1, Whh1p, 8);
        convp(dWih,                       dWih0p, 8);
        convp(dWih + (size_t)4096 * 1024, dWih1p, 8);
        convp(dWhh,                       dWhh0p, 8);
        convp(dWhh + (size_t)4096 * 1024, dWhh1p, 8);
        {
            int total4 = BATCH * SEQ * 32;
            conv_pair_k<<<(total4 + 255) / 256, blk, 0, stream>>>(x, xp, total4, 5);
        }

        hipMemsetAsync(hp0a, 0, 4 * HPSZ * 2 + 2 * CSZ * 4, stream);

        (void)hipFuncSetAttribute(reinterpret_cast<const void*>(&lstm_fused<true>),
                                  hipFuncAttributeMaxDynamicSharedMemorySize, SMEM);

        __bf16 *hc = hp0a, *hn = hp0b, *h1c = hp1a, *h1n = hp1b;
        for (int t = 0; t < SEQ; ++t) {
            lstm_fused<true><<<fgrid, blk, SMEM, stream>>>(
                xp + t * 256, (long long)(SEQ * 256 * 2), DIN, Wih0p,
                hc, Whh0p, b0, c0, hn);
            lstm_fused<true><<<fgrid, blk, SMEM, stream>>>(
                hn, 4096LL, H1, Wih1p, h1c, Whh1p, b1, c1, h1n);
            __bf16* t0 = hc; hc = hn; hn = t0;
            __bf16* t1 = h1c; h1c = h1n; h1n = t1;
        }
        for (int s = 0; s < TDEC; ++s) {
            lstm_fused<true><<<fgrid, blk, SMEM, stream>>>(
                h1c, 4096LL, H1, dWih0p, hc, dWhh0p, db, c0, hn);
            lstm_fused<true><<<fgrid, blk, SMEM, stream>>>(
                hn, 4096LL, H1, dWih1p, h1c, dWhh1p, db + FOURH, c1, h1n);
            __bf16* t0 = hc; hc = hn; hn = t0;
            __bf16* t1 = h1c; h1c = h1n; h1n = t1;
        }
        head2_k<<<dim3(32), blk, 0, stream>>>(h1c, Wout, bout, (float*)d_out);
    } else {
        // ---------------- f32 mode (in-register split, ~12MB ws) ----------------
        float* h0a = (float*)d_ws;
        float* h0b = h0a + CSZ;
        float* h1a = h0b + CSZ;
        float* h1b = h1a + CSZ;
        float* c0  = h1b + CSZ;
        float* c1  = c0 + CSZ;

        hipMemsetAsync(h0a, 0, 6 * CSZ * 4, stream);

        (void)hipFuncSetAttribute(reinterpret_cast<const void*>(&lstm_fused<false>),
                                  hipFuncAttributeMaxDynamicSharedMemorySize, SMEM);

        const float* dWih1 = dWih + (size_t)FOURH * H1;
        const float* dWhh1 = dWhh + (size_t)FOURH * H1;

        float *hc = h0a, *hn = h0b, *h1c = h1a, *h1n = h1b;
        for (int t = 0; t < SEQ; ++t) {
            lstm_fused<false><<<fgrid, blk, SMEM, stream>>>(
                x + (size_t)t * DIN, (long long)(SEQ * DIN * 4), DIN, Wih0,
                hc, Whh0, b0, c0, hn);
            lstm_fused<false><<<fgrid, blk, SMEM, stream>>>(
                hn, 4096LL, H1, Wih1, h1c, Whh1, b1, c1, h1n);
            float* t0 = hc; hc = hn; hn = t0;
            float* t1 = h1c; h1c = h1n; h1n = t1;
        }
        for (int s = 0; s < TDEC; ++s) {
            lstm_fused<false><<<fgrid, blk, SMEM, stream>>>(
                h1c, 4096LL, H1, dWih, hc, dWhh, db, c0, hn);
            lstm_fused<false><<<fgrid, blk, SMEM, stream>>>(
                hn, 4096LL, H1, dWih1, h1c, dWhh1, db + FOURH, c1, h1n);
            float* t0 = hc; hc = hn; hn = t0;
            float* t1 = h1c; h1c = h1n; h1n = t1;
        }
        head_k<<<dim3(32), blk, 0, stream>>>(h1c, Wout, bout, (float*)d_out);
    }
}

// Round 9
// 5189.865 us; speedup vs baseline: 2.4661x; 1.0031x over previous
//
#include <hip/hip_runtime.h>
#include <hip/hip_bf16.h>

#define H1 1024
#define FOURH 4096
#define BATCH 512
#define SEQ 64
#define DIN 128
#define TDEC 8

typedef float f32x4 __attribute__((ext_vector_type(4)));
typedef __bf16 bf16x4 __attribute__((ext_vector_type(4)));
typedef __bf16 bf16x8 __attribute__((ext_vector_type(8)));

// global->LDS direct, 16B per lane. LDS dest is wave-uniform base + lane*16.
__device__ __forceinline__ void gl_lds16(const void* g, void* l) {
    __builtin_amdgcn_global_load_lds(
        (const __attribute__((address_space(1))) unsigned int*)g,
        (__attribute__((address_space(3))) unsigned int*)l, 16, 0, 0);
}

// fp32 [R][K] -> bf16 pair [R][2K] (hi | lo), rows unpermuted (for x).
__global__ __launch_bounds__(256) void conv_pair_k(
    const float* __restrict__ src, __bf16* __restrict__ dst,
    int total4, int k4shift)
{
    int i = blockIdx.x * 256 + threadIdx.x;
    if (i >= total4) return;
    int K4 = 1 << k4shift;
    int r  = i >> k4shift;
    int c4 = i & (K4 - 1);
    int K  = K4 * 4;
    f32x4 v = *(const f32x4*)(src + (size_t)r * K + c4 * 4);
    bf16x4 hi, lo;
#pragma unroll
    for (int e = 0; e < 4; ++e) {
        __bf16 h = (__bf16)v[e];
        hi[e] = h;
        lo[e] = (__bf16)(v[e] - (float)h);
    }
    __bf16* d = dst + (size_t)r * 2 * K;
    *(bf16x4*)(d + c4 * 4)     = hi;
    *(bf16x4*)(d + K + c4 * 4) = lo;
}

// weights [4096][K] -> pair rows PERMUTED: src row r (gate g=r>>10, unit
// u=r&1023) -> dst row (u>>5)*128 + (u&31)*4 + g, so a uc-block's 128
// gate-cols are contiguous and cell reads (i,f,g,o) as one f32x4.
__global__ __launch_bounds__(256) void conv_pair_perm_k(
    const float* __restrict__ src, __bf16* __restrict__ dst,
    int total4, int k4shift)
{
    int i = blockIdx.x * 256 + threadIdx.x;
    if (i >= total4) return;
    int K4 = 1 << k4shift;
    int r  = i >> k4shift;
    int c4 = i & (K4 - 1);
    int K  = K4 * 4;
    f32x4 v = *(const f32x4*)(src + (size_t)r * K + c4 * 4);
    bf16x4 hi, lo;
#pragma unroll
    for (int e = 0; e < 4; ++e) {
        __bf16 h = (__bf16)v[e];
        hi[e] = h;
        lo[e] = (__bf16)(v[e] - (float)h);
    }
    int g = r >> 10, u = r & 1023;
    int dr = (u >> 5) * 128 + (u & 31) * 4 + g;
    __bf16* d = dst + (size_t)dr * 2 * K;
    *(bf16x4*)(d + c4 * 4)     = hi;
    *(bf16x4*)(d + K + c4 * 4) = lo;
}

// ---------------------------------------------------------------------------
// Fused GEMM + LSTM cell. Block = 64 batch x 128 gate-cols (32 units, all 4
// gates; col c -> unit c>>2, gate c&3). grid 256 = 8 bm x 32 uc. 4 waves of
// 32x64 (2x4 frags 16x16x32), every wave computes every chunk.
// 3-term bf16 hi/lo split; PAIR: operands pre-split (weights row-permuted),
// !PAIR: fp32 operands, in-register split, in-kernel row permutation.
// LDS: 6 buffers x (A 8KB + B 16KB) = 144KB; 5-deep prefetch, vmcnt(24)
// ladder (fill-BW: ~30 outstanding 1KB global_load_lds per wave-set).
// Epilogue: acc -> 32KB LDS scratch (buffers 0-1) -> in-block cell.
// ---------------------------------------------------------------------------
template<bool PAIR>
__global__ __launch_bounds__(256, 1) void lstm_fused(
    const void* __restrict__ a0v, long long arow_b, int k0,
    const void* __restrict__ w0v,
    const void* __restrict__ a1v,
    const void* __restrict__ w1v,
    const float* __restrict__ bias,
    float* __restrict__ cst, void* __restrict__ houtv)
{
    extern __shared__ char smem[];            // 6 * 24576 = 147456
    const int tid  = threadIdx.x;
    const int lane = tid & 63;
    const int w    = tid >> 6;                // wave 0..3
    const int wm   = w >> 1, wn = w & 1;      // 2m x 2n -> wave tile 32x64
    const int wg   = blockIdx.x;
    const int bm   = wg >> 5;                 // 0..7 (64-row batch tile)
    const int uc   = wg & 31;                 // 0..31 (32-unit chunk)

    const int nA = k0 >> 5;
    const int n  = nA + (H1 >> 5);

    // ---- staging geometry: 6 gl_lds16 per wave per chunk (A 2 + B 4) ----
    const int rsub = lane >> 3;
    const int slot = lane & 7;
    const int gsw  = slot ^ rsub;             // XOR-swizzled source granule

    long long offA0, offA1, offB0, offB1;
    if constexpr (PAIR) {
        offA0 = (long long)(gsw < 4 ? gsw * 8 : k0 + (gsw - 4) * 8) * 2;
        offA1 = (long long)(gsw < 4 ? gsw * 8 : H1 + (gsw - 4) * 8) * 2;
        offB0 = offA0; offB1 = offA1;
    } else {
        offA0 = offA1 = offB0 = offB1 = gsw * 16;
    }
    const int chunk_b = PAIR ? 64 : 128;      // hi-seg bytes per 32-elem chunk

    const char* paj0[2]; const char* paj1[2];
    const char* pbj0[4]; const char* pbj1[4];
#pragma unroll
    for (int j = 0; j < 2; ++j) {
        int ar = bm * 64 + w * 16 + j * 8 + rsub;
        paj0[j] = (const char*)a0v + (size_t)ar * arow_b + offA0;
        paj1[j] = (const char*)a1v + (size_t)ar * 4096 + offA1;
    }
#pragma unroll
    for (int j = 0; j < 4; ++j) {
        int c = w * 32 + j * 8 + rsub;        // gate-col 0..127
        int br0 = PAIR ? uc * 128 + c : (c & 3) * H1 + uc * 32 + (c >> 2);
        pbj0[j] = (const char*)w0v + (size_t)br0 * (4 * (size_t)k0) + offB0;
        pbj1[j] = (const char*)w1v + (size_t)br0 * 4096 + offB1;
    }

    auto stage = [&](int ii, int buf) {
        char* bufA = smem + buf * 24576;
        char* bufB = bufA + 8192;
        if (ii < nA) {
            size_t kb = (size_t)ii * chunk_b;
            gl_lds16(paj0[0] + kb, bufA + (w * 2    ) * 1024);
            gl_lds16(paj0[1] + kb, bufA + (w * 2 + 1) * 1024);
#pragma unroll
            for (int j = 0; j < 4; ++j)
                gl_lds16(pbj0[j] + kb, bufB + (w * 4 + j) * 1024);
        } else {
            size_t kb = (size_t)(ii - nA) * chunk_b;
            gl_lds16(paj1[0] + kb, bufA + (w * 2    ) * 1024);
            gl_lds16(paj1[1] + kb, bufA + (w * 2 + 1) * 1024);
#pragma unroll
            for (int j = 0; j < 4; ++j)
                gl_lds16(pbj1[j] + kb, bufB + (w * 4 + j) * 1024);
        }
    };

    // ---- fragment geometry ----
    int rA[2], rB[4];
#pragma unroll
    for (int f = 0; f < 2; ++f) rA[f] = wm * 32 + f * 16 + (lane & 15);
#pragma unroll
    for (int f = 0; f < 4; ++f) rB[f] = wn * 64 + f * 16 + (lane & 15);
    const int s7 = lane & 7;
    const int g0 = lane >> 4;                 // k-granule group 0..3

    f32x4 acc[2][4];
#pragma unroll
    for (int mf = 0; mf < 2; ++mf)
#pragma unroll
        for (int nf = 0; nf < 4; ++nf)
            acc[mf][nf] = (f32x4){0.f, 0.f, 0.f, 0.f};

    stage(0, 0); stage(1, 1); stage(2, 2); stage(3, 3); stage(4, 4);

    int buf = 0;
    for (int i = 0; i < n; ++i) {
        // retire chunk i's 6 loads: outstanding = 6*min(5, n-i) -> wait 6*(min-1)
        const int rem = n - i;
        if (rem >= 5)      asm volatile("s_waitcnt vmcnt(24)" ::: "memory");
        else if (rem == 4) asm volatile("s_waitcnt vmcnt(18)" ::: "memory");
        else if (rem == 3) asm volatile("s_waitcnt vmcnt(12)" ::: "memory");
        else if (rem == 2) asm volatile("s_waitcnt vmcnt(6)"  ::: "memory");
        else               asm volatile("s_waitcnt vmcnt(0)"  ::: "memory");
        __builtin_amdgcn_sched_barrier(0);
        __builtin_amdgcn_s_barrier();
        __builtin_amdgcn_sched_barrier(0);

        if (i + 5 < n) {
            int b5 = buf + 5; if (b5 >= 6) b5 -= 6;
            stage(i + 5, b5);
        }

        char* bufA = smem + buf * 24576;
        char* bufB = bufA + 8192;

        bf16x8 ah[2], al[2], bh[4], bl[4];
#pragma unroll
        for (int f = 0; f < 2; ++f) {
            if constexpr (PAIR) {
                ah[f] = *(const bf16x8*)(bufA + rA[f] * 128 + ((g0    ) ^ s7) * 16);
                al[f] = *(const bf16x8*)(bufA + rA[f] * 128 + ((g0 + 4) ^ s7) * 16);
            } else {
                f32x4 v0 = *(const f32x4*)(bufA + rA[f] * 128 + ((2 * g0    ) ^ s7) * 16);
                f32x4 v1 = *(const f32x4*)(bufA + rA[f] * 128 + ((2 * g0 + 1) ^ s7) * 16);
#pragma unroll
                for (int e = 0; e < 4; ++e) {
                    __bf16 h0 = (__bf16)v0[e];
                    ah[f][e] = h0; al[f][e] = (__bf16)(v0[e] - (float)h0);
                    __bf16 h1 = (__bf16)v1[e];
                    ah[f][e + 4] = h1; al[f][e + 4] = (__bf16)(v1[e] - (float)h1);
                }
            }
        }
#pragma unroll
        for (int f = 0; f < 4; ++f) {
            if constexpr (PAIR) {
                bh[f] = *(const bf16x8*)(bufB + rB[f] * 128 + ((g0    ) ^ s7) * 16);
                bl[f] = *(const bf16x8*)(bufB + rB[f] * 128 + ((g0 + 4) ^ s7) * 16);
            } else {
                f32x4 u0 = *(const f32x4*)(bufB + rB[f] * 128 + ((2 * g0    ) ^ s7) * 16);
                f32x4 u1 = *(const f32x4*)(bufB + rB[f] * 128 + ((2 * g0 + 1) ^ s7) * 16);
#pragma unroll
                for (int e = 0; e < 4; ++e) {
                    __bf16 h0 = (__bf16)u0[e];
                    bh[f][e] = h0; bl[f][e] = (__bf16)(u0[e] - (float)h0);
                    __bf16 h1 = (__bf16)u1[e];
                    bh[f][e + 4] = h1; bl[f][e + 4] = (__bf16)(u1[e] - (float)h1);
                }
            }
        }
#pragma unroll
        for (int mf = 0; mf < 2; ++mf)
#pragma unroll
            for (int nf = 0; nf < 4; ++nf) {
                acc[mf][nf] = __builtin_amdgcn_mfma_f32_16x16x32_bf16(
                    ah[mf], bh[nf], acc[mf][nf], 0, 0, 0);
                acc[mf][nf] = __builtin_amdgcn_mfma_f32_16x16x32_bf16(
                    ah[mf], bl[nf], acc[mf][nf], 0, 0, 0);
                acc[mf][nf] = __builtin_amdgcn_mfma_f32_16x16x32_bf16(
                    al[mf], bh[nf], acc[mf][nf], 0, 0, 0);
            }
        __builtin_amdgcn_sched_barrier(0);
        buf = buf + 1; if (buf >= 6) buf -= 6;
    }

    // ---- epilogue: acc -> LDS scratch [64][128] f32 (buffers 0-1) ----
    __syncthreads();
    float* scr = (float*)smem;
#pragma unroll
    for (int mf = 0; mf < 2; ++mf)
#pragma unroll
        for (int nf = 0; nf < 4; ++nf) {
            int row0 = wm * 32 + mf * 16 + (lane >> 4) * 4;   // m89 C layout
            int col  = wn * 64 + nf * 16 + (lane & 15);
#pragma unroll
            for (int j = 0; j < 4; ++j)
                scr[(row0 + j) * 128 + col] = acc[mf][nf][j];
        }
    __syncthreads();

    // ---- in-block LSTM cell: 64 rows x 32 units = 2048 items ----
#pragma unroll
    for (int p = 0; p < 8; ++p) {
        int item = p * 256 + tid;
        int u = item & 31;                    // unit within block
        int r = item >> 5;                    // batch row within block
        f32x4 g4 = *(const f32x4*)(scr + r * 128 + u * 4);
        int gu = uc * 32 + u;                 // global unit 0..1023
        float gi = g4[0] + bias[gu];
        float gf = g4[1] + bias[H1 + gu];
        float gg = g4[2] + bias[2 * H1 + gu];
        float go = g4[3] + bias[3 * H1 + gu];
        float si = 1.f / (1.f + expf(-gi));
        float sf = 1.f / (1.f + expf(-gf));
        float so = 1.f / (1.f + expf(-go));
        int row_g = bm * 64 + r;
        size_t ci = (size_t)row_g * H1 + gu;
        float cc = sf * cst[ci] + si * tanhf(gg);
        cst[ci] = cc;
        float hv = so * tanhf(cc);
        if constexpr (PAIR) {
            __bf16* hp = (__bf16*)houtv;
            __bf16 hh = (__bf16)hv;
            hp[(size_t)row_g * 2048 + gu]        = hh;
            hp[(size_t)row_g * 2048 + 1024 + gu] = (__bf16)(hv - (float)hh);
        } else {
            ((float*)houtv)[(size_t)row_g * H1 + gu] = hv;
        }
    }
}

// head (pair h)
__global__ __launch_bounds__(256) void head2_k(
    const __bf16* __restrict__ hp, const float* __restrict__ W,
    const float* __restrict__ bo, float* __restrict__ out)
{
    int idx = blockIdx.x * 256 + threadIdx.x;
    int b = idx >> 4, o = idx & 15;
    const __bf16* hr = hp + (size_t)b * 2048;
    const f32x4* wv = (const f32x4*)(W + (size_t)o * H1);
    float s = bo[o];
#pragma unroll 4
    for (int k4 = 0; k4 < 128; ++k4) {
        bf16x8 vh = *(const bf16x8*)(hr + k4 * 8);
        bf16x8 vl = *(const bf16x8*)(hr + 1024 + k4 * 8);
        f32x4 w0 = wv[k4 * 2], w1 = wv[k4 * 2 + 1];
#pragma unroll
        for (int e = 0; e < 4; ++e)
            s += ((float)vh[e] + (float)vl[e]) * w0[e];
#pragma unroll
        for (int e = 4; e < 8; ++e)
            s += ((float)vh[e] + (float)vl[e]) * w1[e - 4];
    }
    out[(size_t)b * 32 + o]      = s;
    out[(size_t)b * 32 + 16 + o] = s;
}

// head (f32 h)
__global__ __launch_bounds__(256) void head_k(
    const float* __restrict__ h, const float* __restrict__ W,
    const float* __restrict__ bo, float* __restrict__ out)
{
    int idx = blockIdx.x * 256 + threadIdx.x;
    int b = idx >> 4, o = idx & 15;
    const f32x4* hv = (const f32x4*)(h + (size_t)b * H1);
    const f32x4* wv = (const f32x4*)(W + (size_t)o * H1);
    float s = bo[o];
#pragma unroll 4
    for (int k = 0; k < H1 / 4; ++k) {
        f32x4 a = hv[k];
        f32x4 wq = wv[k];
        s += a[0] * wq[0] + a[1] * wq[1] + a[2] * wq[2] + a[3] * wq[3];
    }
    out[(size_t)b * 32 + o]      = s;
    out[(size_t)b * 32 + 16 + o] = s;
}

// ===========================================================================
extern "C" void kernel_launch(void* const* d_in, const int* in_sizes, int n_in,
                              void* d_out, int out_size, void* d_ws, size_t ws_size,
                              hipStream_t stream)
{
    const float* x    = (const float*)d_in[0];
    const float* Wih0 = (const float*)d_in[1];
    const float* Whh0 = (const float*)d_in[2];
    const float* b0   = (const float*)d_in[3];
    const float* Wih1 = (const float*)d_in[4];
    const float* Whh1 = (const float*)d_in[5];
    const float* b1   = (const float*)d_in[6];
    const float* dWih = (const float*)d_in[7];
    const float* dWhh = (const float*)d_in[8];
    const float* db   = (const float*)d_in[9];
    const float* Wout = (const float*)d_in[10];
    const float* bout = (const float*)d_in[11];

    dim3 blk(256);
    dim3 fgrid(256);
    const size_t SMEM = 147456;

    const size_t W0SZ = (size_t)4096 * 256;
    const size_t WBSZ = (size_t)4096 * 2048;
    const size_t XPSZ = (size_t)BATCH * SEQ * 256;
    const size_t HPSZ = (size_t)BATCH * 2048;
    const size_t CSZ  = (size_t)BATCH * H1;
    const size_t NEED = (W0SZ + 7 * WBSZ + XPSZ) * 2 + 4 * HPSZ * 2 + 2 * CSZ * 4;

    if (ws_size >= NEED) {
        // ---------------- pair mode ----------------
        __bf16* Wih0p  = (__bf16*)d_ws;
        __bf16* Whh0p  = Wih0p + W0SZ;
        __bf16* Wih1p  = Whh0p + WBSZ;
        __bf16* Whh1p  = Wih1p + WBSZ;
        __bf16* dWih0p = Whh1p + WBSZ;
        __bf16* dWhh0p = dWih0p + WBSZ;
        __bf16* dWih1p = dWhh0p + WBSZ;
        __bf16* dWhh1p = dWih1p + WBSZ;
        __bf16* xp     = dWhh1p + WBSZ;
        __bf16* hp0a   = xp + XPSZ;
        __bf16* hp0b   = hp0a + HPSZ;
        __bf16* hp1a   = hp0b + HPSZ;
        __bf16* hp1b   = hp1a + HPSZ;
        float*  c0     = (float*)(hp1b + HPSZ);
        float*  c1     = c0 + CSZ;

        auto convp = [&](const float* s, __bf16* d, int shift) {
            int total4 = 4096 * (1 << shift);
            conv_pair_perm_k<<<(total4 + 255) / 256, blk, 0, stream>>>(s, d, total4, shift);
        };
        convp(Wih0, Wih0p, 5);
        convp(Whh0, Whh0p, 8);
        convp(Wih1, Wih1p, 8);
        convp(Whh1, Whh1p, 8);
        convp(dWih,                       dWih0p, 8);
        convp(dWih + (size_t)4096 * 1024, dWih1p, 8);
        convp(dWhh,                       dWhh0p, 8);
        convp(dWhh + (size_t)4096 * 1024, dWhh1p, 8);
        {
            int total4 = BATCH * SEQ * 32;
            conv_pair_k<<<(total4 + 255) / 256, blk, 0, stream>>>(x, xp, total4, 5);
        }

        hipMemsetAsync(hp0a, 0, 4 * HPSZ * 2 + 2 * CSZ * 4, stream);

        (void)hipFuncSetAttribute(reinterpret_cast<const void*>(&lstm_fused<true>),
                                  hipFuncAttributeMaxDynamicSharedMemorySize, SMEM);

        __bf16 *hc = hp0a, *hn = hp0b, *h1c = hp1a, *h1n = hp1b;
        for (int t = 0; t < SEQ; ++t) {
            lstm_fused<true><<<fgrid, blk, SMEM, stream>>>(
                xp + t * 256, (long long)(SEQ * 256 * 2), DIN, Wih0p,
                hc, Whh0p, b0, c0, hn);
            lstm_fused<true><<<fgrid, blk, SMEM, stream>>>(
                hn, 4096LL, H1, Wih1p, h1c, Whh1p, b1, c1, h1n);
            __bf16* t0 = hc; hc = hn; hn = t0;
            __bf16* t1 = h1c; h1c = h1n; h1n = t1;
        }
        for (int s = 0; s < TDEC; ++s) {
            lstm_fused<true><<<fgrid, blk, SMEM, stream>>>(
                h1c, 4096LL, H1, dWih0p, hc, dWhh0p, db, c0, hn);
            lstm_fused<true><<<fgrid, blk, SMEM, stream>>>(
                hn, 4096LL, H1, dWih1p, h1c, dWhh1p, db + FOURH, c1, h1n);
            __bf16* t0 = hc; hc = hn; hn = t0;
            __bf16* t1 = h1c; h1c = h1n; h1n = t1;
        }
        head2_k<<<dim3(32), blk, 0, stream>>>(h1c, Wout, bout, (float*)d_out);
    } else {
        // ---------------- f32 mode (in-register split, ~12MB ws) ----------------
        float* h0a = (float*)d_ws;
        float* h0b = h0a + CSZ;
        float* h1a = h0b + CSZ;
        float* h1b = h1a + CSZ;
        float* c0  = h1b + CSZ;
        float* c1  = c0 + CSZ;

        hipMemsetAsync(h0a, 0, 6 * CSZ * 4, stream);

        (void)hipFuncSetAttribute(reinterpret_cast<const void*>(&lstm_fused<false>),
                                  hipFuncAttributeMaxDynamicSharedMemorySize, SMEM);

        const float* dWih1 = dWih + (size_t)FOURH * H1;
        const float* dWhh1 = dWhh + (size_t)FOURH * H1;

        float *hc = h0a, *hn = h0b, *h1c = h1a, *h1n = h1b;
        for (int t = 0; t < SEQ; ++t) {
            lstm_fused<false><<<fgrid, blk, SMEM, stream>>>(
                x + (size_t)t * DIN, (long long)(SEQ * DIN * 4), DIN, Wih0,
                hc, Whh0, b0, c0, hn);
            lstm_fused<false><<<fgrid, blk, SMEM, stream>>>(
                hn, 4096LL, H1, Wih1, h1c, Whh1, b1, c1, h1n);
            float* t0 = hc; hc = hn; hn = t0;
            float* t1 = h1c; h1c = h1n; h1n = t1;
        }
        for (int s = 0; s < TDEC; ++s) {
            lstm_fused<false><<<fgrid, blk, SMEM, stream>>>(
                h1c, 4096LL, H1, dWih, hc, dWhh, db, c0, hn);
            lstm_fused<false><<<fgrid, blk, SMEM, stream>>>(
                hn, 4096LL, H1, dWih1, h1c, dWhh1, db + FOURH, c1, h1n);
            float* t0 = hc; hc = hn; hn = t0;
            float* t1 = h1c; h1c = h1n; h1n = t1;
        }
        head_k<<<dim3(32), blk, 0, stream>>>(h1c, Wout, bout, (float*)d_out);
    }
}

// Round 10
// 5117.168 us; speedup vs baseline: 2.5011x; 1.0142x over previous
//
#include <hip/hip_runtime.h>
#include <hip/hip_bf16.h>

#define H1 1024
#define FOURH 4096
#define BATCH 512
#define SEQ 64
#define DIN 128
#define TDEC 8
#define SCR 68

typedef float f32x4 __attribute__((ext_vector_type(4)));
typedef __bf16 bf16x8 __attribute__((ext_vector_type(8)));

// global->LDS direct, 16B per lane. LDS dest is wave-uniform base + lane*16.
__device__ __forceinline__ void gl_lds16(const void* g, void* l) {
    __builtin_amdgcn_global_load_lds(
        (const __attribute__((address_space(1))) unsigned int*)g,
        (__attribute__((address_space(3))) unsigned int*)l, 16, 0, 0);
}

// ---------------------------------------------------------------------------
// W [4096][K] f32 -> fragment-ordered bf16 hi/lo pieces for 16-unit blocks.
// uc (0..63) owns units uc*16..+16, cols c = (u&15)*4 + gate (64 cols).
// Piece (kk,t,g,c) = elems k = kk*32+g*8..+8 of col c, t=0 hi / t=1 lo,
// stored at elem offset ((kk*8 + t*4 + g)*64 + c)*8 within uc block
// (uc stride K*128 elems). GEMM lane (g=lane>>4, c=wn*32+f*16+(lane&15))
// then reads its 16B with quarter-wave-contiguous addresses.
// ---------------------------------------------------------------------------
__global__ __launch_bounds__(256) void conv_frag_k(
    const float* __restrict__ src, __bf16* __restrict__ dst, int K, int ks5)
{
    int i = blockIdx.x * 256 + threadIdx.x;
    int c  = i & 63;
    int g  = (i >> 6) & 3;
    int t  = (i >> 8) & 1;
    int kk = (i >> 9) & ((1 << ks5) - 1);
    int uc = i >> (9 + ks5);
    int gate = c & 3;
    int u = uc * 16 + (c >> 2);
    int r = gate * 1024 + u;
    const float* s = src + (size_t)r * K + kk * 32 + g * 8;
    bf16x8 p;
#pragma unroll
    for (int e = 0; e < 8; ++e) {
        float v = s[e];
        __bf16 h = (__bf16)v;
        p[e] = t ? (__bf16)(v - (float)h) : h;
    }
    *(bf16x8*)(dst + (size_t)uc * ((size_t)K * 128)
               + ((size_t)((kk * 8 + t * 4 + g) * 64 + c)) * 8) = p;
}

// ---------------------------------------------------------------------------
// Fused GEMM + LSTM cell, B-direct-to-registers variant.
// grid 512 = 8 bm (64 batch) x 64 uc (16 units -> 64 gate-cols). 4 waves
// (2m x 2n), wave tile 32x32 (2x2 frags of 16x16x32). 2 blocks/CU.
// A (fp32 x or h) staged via gl_lds16, 4 x 8KB buffers, XOR-swizzled,
// in-register hi/lo split. B loaded direct from frag-ordered ws, 2 reg sets.
// Epilogue: acc -> LDS scratch -> in-block cell -> fp32 h out.
// ---------------------------------------------------------------------------
__global__ __launch_bounds__(256, 2) void lstm_fb(
    const float* __restrict__ a0, long long arow_b, int k0,
    const __bf16* __restrict__ w0f,
    const float* __restrict__ a1,
    const __bf16* __restrict__ w1f,
    const float* __restrict__ bias,
    float* __restrict__ cst, float* __restrict__ hout)
{
    __shared__ char smem[32768];
    const int tid  = threadIdx.x;
    const int lane = tid & 63;
    const int w    = tid >> 6;                // wave 0..3
    const int wm   = w >> 1, wn = w & 1;
    const int wg   = blockIdx.x;
    const int bm   = wg >> 6;                 // 0..7
    const int uc   = wg & 63;                 // 0..63 (wg%8 = uc%8 -> same-XCD B sharing)

    const int nA = k0 >> 5;
    const int n  = nA + 32;

    // A staging geometry
    const int rsub = lane >> 3;
    const int slot = lane & 7;
    const int gsw  = slot ^ rsub;             // XOR-swizzled source granule
    const char* pa0j[2];
    const char* pa1j[2];
#pragma unroll
    for (int j = 0; j < 2; ++j) {
        int row = bm * 64 + w * 16 + j * 8 + rsub;
        pa0j[j] = (const char*)a0 + (size_t)row * arow_b + gsw * 16;
        pa1j[j] = (const char*)a1 + (size_t)row * 4096 + gsw * 16;
    }
    auto stage = [&](int ii, int buf) {
        char* d = smem + buf * 8192 + w * 2048;
        if (ii < nA) {
            size_t kb = (size_t)ii * 128;
            gl_lds16(pa0j[0] + kb, d);
            gl_lds16(pa0j[1] + kb, d + 1024);
        } else {
            size_t kb = (size_t)(ii - nA) * 128;
            gl_lds16(pa1j[0] + kb, d);
            gl_lds16(pa1j[1] + kb, d + 1024);
        }
    };

    // B per-lane base pointers (frag-ordered)
    const int g0 = lane >> 4;
    const size_t lnoff = (size_t)(g0 * 1024 + (wn * 32 + (lane & 15)) * 16);
    const char* pB0 = (const char*)w0f + (size_t)uc * (256 * (size_t)k0) + lnoff;
    const char* pB1 = (const char*)w1f + (size_t)uc * 262144 + lnoff;

    f32x4 acc[2][2];
#pragma unroll
    for (int a = 0; a < 2; ++a)
#pragma unroll
        for (int b = 0; b < 2; ++b)
            acc[a][b] = (f32x4){0.f, 0.f, 0.f, 0.f};

    bf16x8 B0h[2], B0l[2], B1h[2], B1l[2];

    // prologue: B(0) first (oldest in FIFO), then A(0..2)
    {
        const char* q_ = pB0;                 // chunk 0 always in segment 0
        B0h[0] = *(const bf16x8*)(q_);
        B0h[1] = *(const bf16x8*)(q_ + 256);
        B0l[0] = *(const bf16x8*)(q_ + 4096);
        B0l[1] = *(const bf16x8*)(q_ + 4096 + 256);
    }
    stage(0, 0); stage(1, 1); stage(2, 2);

#define CHUNK_BODY(J, CH, CL, NH, NL)                                         \
    {                                                                         \
        if ((J) == 0) asm volatile("s_waitcnt vmcnt(4)" ::: "memory");        \
        else          asm volatile("s_waitcnt vmcnt(8)" ::: "memory");        \
        __builtin_amdgcn_sched_barrier(0);                                    \
        __builtin_amdgcn_s_barrier();                                         \
        __builtin_amdgcn_sched_barrier(0);                                    \
        if ((J) + 1 < n) {                                                    \
            const char* q_ = ((J) + 1 < nA)                                   \
                ? pB0 + (size_t)((J) + 1) * 8192                              \
                : pB1 + (size_t)((J) + 1 - nA) * 8192;                        \
            NH[0] = *(const bf16x8*)(q_);                                     \
            NH[1] = *(const bf16x8*)(q_ + 256);                               \
            NL[0] = *(const bf16x8*)(q_ + 4096);                              \
            NL[1] = *(const bf16x8*)(q_ + 4096 + 256);                        \
        }                                                                     \
        if ((J) + 3 < n) stage((J) + 3, ((J) + 3) & 3);                       \
        {                                                                     \
            const char* bA_ = smem + ((J) & 3) * 8192;                        \
            bf16x8 ah_[2], al_[2];                                            \
            _Pragma("unroll")                                                 \
            for (int f_ = 0; f_ < 2; ++f_) {                                  \
                int r_  = wm * 32 + f_ * 16 + (lane & 15);                    \
                int sx_ = r_ & 7;                                             \
                f32x4 v0_ = *(const f32x4*)(bA_ + r_ * 128 + ((2 * g0    ) ^ sx_) * 16); \
                f32x4 v1_ = *(const f32x4*)(bA_ + r_ * 128 + ((2 * g0 + 1) ^ sx_) * 16); \
                _Pragma("unroll")                                             \
                for (int e_ = 0; e_ < 4; ++e_) {                              \
                    __bf16 h0_ = (__bf16)v0_[e_];                             \
                    ah_[f_][e_] = h0_;                                        \
                    al_[f_][e_] = (__bf16)(v0_[e_] - (float)h0_);             \
                    __bf16 h1_ = (__bf16)v1_[e_];                             \
                    ah_[f_][e_ + 4] = h1_;                                    \
                    al_[f_][e_ + 4] = (__bf16)(v1_[e_] - (float)h1_);         \
                }                                                             \
            }                                                                 \
            _Pragma("unroll")                                                 \
            for (int mf_ = 0; mf_ < 2; ++mf_)                                 \
                _Pragma("unroll")                                             \
                for (int nf_ = 0; nf_ < 2; ++nf_) {                           \
                    acc[mf_][nf_] = __builtin_amdgcn_mfma_f32_16x16x32_bf16(  \
                        ah_[mf_], CH[nf_], acc[mf_][nf_], 0, 0, 0);           \
                    acc[mf_][nf_] = __builtin_amdgcn_mfma_f32_16x16x32_bf16(  \
                        ah_[mf_], CL[nf_], acc[mf_][nf_], 0, 0, 0);           \
                    acc[mf_][nf_] = __builtin_amdgcn_mfma_f32_16x16x32_bf16(  \
                        al_[mf_], CH[nf_], acc[mf_][nf_], 0, 0, 0);           \
                }                                                             \
        }                                                                     \
    }

    for (int i = 0; i < n; i += 2) {          // n is even (36 or 64)
        CHUNK_BODY(i,     B0h, B0l, B1h, B1l);
        CHUNK_BODY(i + 1, B1h, B1l, B0h, B0l);
    }
#undef CHUNK_BODY

    // ---- epilogue: acc -> LDS scratch [64][SCR] f32 ----
    __syncthreads();
    float* scr = (float*)smem;                // 64*68*4 = 17408 B
#pragma unroll
    for (int mf = 0; mf < 2; ++mf)
#pragma unroll
        for (int nf = 0; nf < 2; ++nf) {
            int row0 = wm * 32 + mf * 16 + (lane >> 4) * 4;  // m89 C layout
            int col  = wn * 32 + nf * 16 + (lane & 15);
#pragma unroll
            for (int j = 0; j < 4; ++j)
                scr[(row0 + j) * SCR + col] = acc[mf][nf][j];
        }
    __syncthreads();

    // ---- in-block cell: 64 rows x 16 units = 1024 items ----
#pragma unroll
    for (int p = 0; p < 4; ++p) {
        int item = p * 256 + tid;
        int u = item & 15;
        int r = item >> 4;                    // 0..63
        f32x4 g4 = *(const f32x4*)(scr + r * SCR + u * 4);
        int gu = uc * 16 + u;
        float gi = g4[0] + bias[gu];
        float gf = g4[1] + bias[H1 + gu];
        float gg = g4[2] + bias[2 * H1 + gu];
        float go = g4[3] + bias[3 * H1 + gu];
        float si = 1.f / (1.f + expf(-gi));
        float sf = 1.f / (1.f + expf(-gf));
        float so = 1.f / (1.f + expf(-go));
        size_t ci = (size_t)(bm * 64 + r) * H1 + gu;
        float cc = sf * cst[ci] + si * tanhf(gg);
        cst[ci] = cc;
        hout[ci] = so * tanhf(cc);
    }
}

// ---------------------------------------------------------------------------
// FALLBACK (r8/r9-proven f32 path, grid 256, full-LDS staging) — distinct
// name so the profile identifies which tier ran.
// ---------------------------------------------------------------------------
__global__ __launch_bounds__(256, 1) void lstm_fused_f32(
    const float* __restrict__ a0v, long long arow_b, int k0,
    const float* __restrict__ w0v,
    const float* __restrict__ a1v,
    const float* __restrict__ w1v,
    const float* __restrict__ bias,
    float* __restrict__ cst, float* __restrict__ houtv)
{
    extern __shared__ char smem[];            // 6 * 24576
    const int tid  = threadIdx.x;
    const int lane = tid & 63;
    const int w    = tid >> 6;
    const int wm   = w >> 1, wn = w & 1;
    const int wg   = blockIdx.x;
    const int bm   = wg >> 5;
    const int uc   = wg & 31;

    const int nA = k0 >> 5;
    const int n  = nA + 32;

    const int rsub = lane >> 3;
    const int slot = lane & 7;
    const int gsw  = slot ^ rsub;

    const char* paj0[2]; const char* paj1[2];
    const char* pbj0[4]; const char* pbj1[4];
#pragma unroll
    for (int j = 0; j < 2; ++j) {
        int ar = bm * 64 + w * 16 + j * 8 + rsub;
        paj0[j] = (const char*)a0v + (size_t)ar * arow_b + gsw * 16;
        paj1[j] = (const char*)a1v + (size_t)ar * 4096 + gsw * 16;
    }
#pragma unroll
    for (int j = 0; j < 4; ++j) {
        int c = w * 32 + j * 8 + rsub;
        int br0 = (c & 3) * H1 + uc * 32 + (c >> 2);
        pbj0[j] = (const char*)w0v + (size_t)br0 * (4 * (size_t)k0) + gsw * 16;
        pbj1[j] = (const char*)w1v + (size_t)br0 * 4096 + gsw * 16;
    }

    auto stage = [&](int ii, int buf) {
        char* bufA = smem + buf * 24576;
        char* bufB = bufA + 8192;
        if (ii < nA) {
            size_t kb = (size_t)ii * 128;
            gl_lds16(paj0[0] + kb, bufA + (w * 2    ) * 1024);
            gl_lds16(paj0[1] + kb, bufA + (w * 2 + 1) * 1024);
#pragma unroll
            for (int j = 0; j < 4; ++j)
                gl_lds16(pbj0[j] + kb, bufB + (w * 4 + j) * 1024);
        } else {
            size_t kb = (size_t)(ii - nA) * 128;
            gl_lds16(paj1[0] + kb, bufA + (w * 2    ) * 1024);
            gl_lds16(paj1[1] + kb, bufA + (w * 2 + 1) * 1024);
#pragma unroll
            for (int j = 0; j < 4; ++j)
                gl_lds16(pbj1[j] + kb, bufB + (w * 4 + j) * 1024);
        }
    };

    int rAv[2], rBv[4];
#pragma unroll
    for (int f = 0; f < 2; ++f) rAv[f] = wm * 32 + f * 16 + (lane & 15);
#pragma unroll
    for (int f = 0; f < 4; ++f) rBv[f] = wn * 64 + f * 16 + (lane & 15);
    const int s7 = lane & 7;
    const int g0 = lane >> 4;

    f32x4 acc[2][4];
#pragma unroll
    for (int mf = 0; mf < 2; ++mf)
#pragma unroll
        for (int nf = 0; nf < 4; ++nf)
            acc[mf][nf] = (f32x4){0.f, 0.f, 0.f, 0.f};

    stage(0, 0); stage(1, 1); stage(2, 2); stage(3, 3); stage(4, 4);

    int buf = 0;
    for (int i = 0; i < n; ++i) {
        const int rem = n - i;
        if (rem >= 5)      asm volatile("s_waitcnt vmcnt(24)" ::: "memory");
        else if (rem == 4) asm volatile("s_waitcnt vmcnt(18)" ::: "memory");
        else if (rem == 3) asm volatile("s_waitcnt vmcnt(12)" ::: "memory");
        else if (rem == 2) asm volatile("s_waitcnt vmcnt(6)"  ::: "memory");
        else               asm volatile("s_waitcnt vmcnt(0)"  ::: "memory");
        __builtin_amdgcn_sched_barrier(0);
        __builtin_amdgcn_s_barrier();
        __builtin_amdgcn_sched_barrier(0);

        if (i + 5 < n) {
            int b5 = buf + 5; if (b5 >= 6) b5 -= 6;
            stage(i + 5, b5);
        }

        char* bufA = smem + buf * 24576;
        char* bufB = bufA + 8192;

        bf16x8 ah[2], al[2], bh[4], bl[4];
#pragma unroll
        for (int f = 0; f < 2; ++f) {
            f32x4 v0 = *(const f32x4*)(bufA + rAv[f] * 128 + ((2 * g0    ) ^ s7) * 16);
            f32x4 v1 = *(const f32x4*)(bufA + rAv[f] * 128 + ((2 * g0 + 1) ^ s7) * 16);
#pragma unroll
            for (int e = 0; e < 4; ++e) {
                __bf16 h0 = (__bf16)v0[e];
                ah[f][e] = h0; al[f][e] = (__bf16)(v0[e] - (float)h0);
                __bf16 h1 = (__bf16)v1[e];
                ah[f][e + 4] = h1; al[f][e + 4] = (__bf16)(v1[e] - (float)h1);
            }
        }
#pragma unroll
        for (int f = 0; f < 4; ++f) {
            f32x4 u0 = *(const f32x4*)(bufB + rBv[f] * 128 + ((2 * g0    ) ^ s7) * 16);
            f32x4 u1 = *(const f32x4*)(bufB + rBv[f] * 128 + ((2 * g0 + 1) ^ s7) * 16);
#pragma unroll
            for (int e = 0; e < 4; ++e) {
                __bf16 h0 = (__bf16)u0[e];
                bh[f][e] = h0; bl[f][e] = (__bf16)(u0[e] - (float)h0);
                __bf16 h1 = (__bf16)u1[e];
                bh[f][e + 4] = h1; bl[f][e + 4] = (__bf16)(u1[e] - (float)h1);
            }
        }
#pragma unroll
        for (int mf = 0; mf < 2; ++mf)
#pragma unroll
            for (int nf = 0; nf < 4; ++nf) {
                acc[mf][nf] = __builtin_amdgcn_mfma_f32_16x16x32_bf16(
                    ah[mf], bh[nf], acc[mf][nf], 0, 0, 0);
                acc[mf][nf] = __builtin_amdgcn_mfma_f32_16x16x32_bf16(
                    ah[mf], bl[nf], acc[mf][nf], 0, 0, 0);
                acc[mf][nf] = __builtin_amdgcn_mfma_f32_16x16x32_bf16(
                    al[mf], bh[nf], acc[mf][nf], 0, 0, 0);
            }
        __builtin_amdgcn_sched_barrier(0);
        buf = buf + 1; if (buf >= 6) buf -= 6;
    }

    __syncthreads();
    float* scr = (float*)smem;
#pragma unroll
    for (int mf = 0; mf < 2; ++mf)
#pragma unroll
        for (int nf = 0; nf < 4; ++nf) {
            int row0 = wm * 32 + mf * 16 + (lane >> 4) * 4;
            int col  = wn * 64 + nf * 16 + (lane & 15);
#pragma unroll
            for (int j = 0; j < 4; ++j)
                scr[(row0 + j) * 128 + col] = acc[mf][nf][j];
        }
    __syncthreads();

#pragma unroll
    for (int p = 0; p < 8; ++p) {
        int item = p * 256 + tid;
        int u = item & 31;
        int r = item >> 5;
        f32x4 g4 = *(const f32x4*)(scr + r * 128 + u * 4);
        int gu = uc * 32 + u;
        float gi = g4[0] + bias[gu];
        float gf = g4[1] + bias[H1 + gu];
        float gg = g4[2] + bias[2 * H1 + gu];
        float go = g4[3] + bias[3 * H1 + gu];
        float si = 1.f / (1.f + expf(-gi));
        float sf = 1.f / (1.f + expf(-gf));
        float so = 1.f / (1.f + expf(-go));
        size_t ci = (size_t)(bm * 64 + r) * H1 + gu;
        float cc = sf * cst[ci] + si * tanhf(gg);
        cst[ci] = cc;
        houtv[ci] = so * tanhf(cc);
    }
}

__global__ __launch_bounds__(256) void head_k(
    const float* __restrict__ h, const float* __restrict__ W,
    const float* __restrict__ bo, float* __restrict__ out)
{
    int idx = blockIdx.x * 256 + threadIdx.x;
    int b = idx >> 4, o = idx & 15;
    const f32x4* hv = (const f32x4*)(h + (size_t)b * H1);
    const f32x4* wv = (const f32x4*)(W + (size_t)o * H1);
    float s = bo[o];
#pragma unroll 4
    for (int k = 0; k < H1 / 4; ++k) {
        f32x4 a = hv[k];
        f32x4 wq = wv[k];
        s += a[0] * wq[0] + a[1] * wq[1] + a[2] * wq[2] + a[3] * wq[3];
    }
    out[(size_t)b * 32 + o]      = s;
    out[(size_t)b * 32 + 16 + o] = s;
}

// ===========================================================================
extern "C" void kernel_launch(void* const* d_in, const int* in_sizes, int n_in,
                              void* d_out, int out_size, void* d_ws, size_t ws_size,
                              hipStream_t stream)
{
    const float* x    = (const float*)d_in[0];
    const float* Wih0 = (const float*)d_in[1];
    const float* Whh0 = (const float*)d_in[2];
    const float* b0   = (const float*)d_in[3];
    const float* Wih1 = (const float*)d_in[4];
    const float* Whh1 = (const float*)d_in[5];
    const float* b1   = (const float*)d_in[6];
    const float* dWih = (const float*)d_in[7];
    const float* dWhh = (const float*)d_in[8];
    const float* db   = (const float*)d_in[9];
    const float* Wout = (const float*)d_in[10];
    const float* bout = (const float*)d_in[11];

    dim3 blk(256);
    const size_t FR_SMALL = (size_t)128 * 16384;   // 2MB  (K=128 frag)
    const size_t FR_BIG   = (size_t)1024 * 16384;  // 16MB (K=1024 frag)
    const size_t CSZ      = (size_t)BATCH * H1;    // 2M f32 elems = 8MB? (elems)
    const size_t STATE_B  = 6 * CSZ * 4;           // h0a,h0b,h1a,h1b,c0,c1 = 12MB

    const size_t NEED1 = FR_SMALL + 7 * FR_BIG + STATE_B;  // 126MB
    const size_t NEED2 = FR_SMALL + 3 * FR_BIG + STATE_B;  // 62MB

    const float* dWih1 = dWih + (size_t)FOURH * H1;
    const float* dWhh1 = dWhh + (size_t)FOURH * H1;

    int tier = (ws_size >= NEED1) ? 1 : (ws_size >= NEED2) ? 2 : 3;

    char* wsb = (char*)d_ws;
    __bf16 *Wih0f = nullptr, *Whh0f = nullptr, *Wih1f = nullptr, *Whh1f = nullptr;
    __bf16 *dWih0f = nullptr, *dWhh0f = nullptr, *dWih1f = nullptr, *dWhh1f = nullptr;
    float* stateBase;

    auto convf = [&](const float* s, __bf16* d, int K, int ks5) {
        int total = 1024 * K;                 // pieces
        conv_frag_k<<<dim3(total / 256), blk, 0, stream>>>(s, d, K, ks5);
    };

    if (tier == 1) {
        Wih0f  = (__bf16*)wsb;
        Whh0f  = (__bf16*)(wsb + FR_SMALL);
        Wih1f  = (__bf16*)(wsb + FR_SMALL + FR_BIG);
        Whh1f  = (__bf16*)(wsb + FR_SMALL + 2 * FR_BIG);
        dWih0f = (__bf16*)(wsb + FR_SMALL + 3 * FR_BIG);
        dWhh0f = (__bf16*)(wsb + FR_SMALL + 4 * FR_BIG);
        dWih1f = (__bf16*)(wsb + FR_SMALL + 5 * FR_BIG);
        dWhh1f = (__bf16*)(wsb + FR_SMALL + 6 * FR_BIG);
        stateBase = (float*)(wsb + FR_SMALL + 7 * FR_BIG);
        convf(Wih0, Wih0f, 128, 2);
        convf(Whh0, Whh0f, 1024, 5);
        convf(Wih1, Wih1f, 1024, 5);
        convf(Whh1, Whh1f, 1024, 5);
        convf(dWih,  dWih0f, 1024, 5);
        convf(dWih1, dWih1f, 1024, 5);
        convf(dWhh,  dWhh0f, 1024, 5);
        convf(dWhh1, dWhh1f, 1024, 5);
    } else if (tier == 2) {
        Wih0f = (__bf16*)wsb;
        Whh0f = (__bf16*)(wsb + FR_SMALL);
        Wih1f = (__bf16*)(wsb + FR_SMALL + FR_BIG);
        Whh1f = (__bf16*)(wsb + FR_SMALL + 2 * FR_BIG);
        stateBase = (float*)(wsb + FR_SMALL + 3 * FR_BIG);
        convf(Wih0, Wih0f, 128, 2);
        convf(Whh0, Whh0f, 1024, 5);
        convf(Wih1, Wih1f, 1024, 5);
        convf(Whh1, Whh1f, 1024, 5);
    } else {
        stateBase = (float*)wsb;
    }

    float* h0a = stateBase;
    float* h0b = h0a + CSZ;
    float* h1a = h0b + CSZ;
    float* h1b = h1a + CSZ;
    float* c0  = h1b + CSZ;
    float* c1  = c0 + CSZ;
    hipMemsetAsync(h0a, 0, STATE_B, stream);

    (void)hipFuncSetAttribute(reinterpret_cast<const void*>(&lstm_fused_f32),
                              hipFuncAttributeMaxDynamicSharedMemorySize, 147456);

    dim3 fbgrid(512);
    dim3 oldgrid(256);
    float *hc = h0a, *hn = h0b, *h1c = h1a, *h1n = h1b;

    if (tier <= 2) {
        for (int t = 0; t < SEQ; ++t) {
            lstm_fb<<<fbgrid, blk, 0, stream>>>(
                x + (size_t)t * DIN, (long long)(SEQ * DIN * 4), DIN, Wih0f,
                hc, Whh0f, b0, c0, hn);
            lstm_fb<<<fbgrid, blk, 0, stream>>>(
                hn, 4096LL, H1, Wih1f, h1c, Whh1f, b1, c1, h1n);
            float* t0 = hc; hc = hn; hn = t0;
            float* t1 = h1c; h1c = h1n; h1n = t1;
        }
        for (int s = 0; s < TDEC; ++s) {
            if (tier == 1) {
                lstm_fb<<<fbgrid, blk, 0, stream>>>(
                    h1c, 4096LL, H1, dWih0f, hc, dWhh0f, db, c0, hn);
                lstm_fb<<<fbgrid, blk, 0, stream>>>(
                    hn, 4096LL, H1, dWih1f, h1c, dWhh1f, db + FOURH, c1, h1n);
            } else {
                lstm_fused_f32<<<oldgrid, blk, 147456, stream>>>(
                    h1c, 4096LL, H1, dWih, hc, dWhh, db, c0, hn);
                lstm_fused_f32<<<oldgrid, blk, 147456, stream>>>(
                    hn, 4096LL, H1, dWih1, h1c, dWhh1, db + FOURH, c1, h1n);
            }
            float* t0 = hc; hc = hn; hn = t0;
            float* t1 = h1c; h1c = h1n; h1n = t1;
        }
    } else {
        for (int t = 0; t < SEQ; ++t) {
            lstm_fused_f32<<<oldgrid, blk, 147456, stream>>>(
                x + (size_t)t * DIN, (long long)(SEQ * DIN * 4), DIN, Wih0,
                hc, Whh0, b0, c0, hn);
            lstm_fused_f32<<<oldgrid, blk, 147456, stream>>>(
                hn, 4096LL, H1, Wih1, h1c, Whh1, b1, c1, h1n);
            float* t0 = hc; hc = hn; hn = t0;
            float* t1 = h1c; h1c = h1n; h1n = t1;
        }
        for (int s = 0; s < TDEC; ++s) {
            lstm_fused_f32<<<oldgrid, blk, 147456, stream>>>(
                h1c, 4096LL, H1, dWih, hc, dWhh, db, c0, hn);
            lstm_fused_f32<<<oldgrid, blk, 147456, stream>>>(
                hn, 4096LL, H1, dWih1, h1c, dWhh1, db + FOURH, c1, h1n);
            float* t0 = hc; hc = hn; hn = t0;
            float* t1 = h1c; h1c = h1n; h1n = t1;
        }
    }

    head_k<<<dim3(32), blk, 0, stream>>>(h1c, Wout, bout, (float*)d_out);
}

// Round 12
// 4350.310 us; speedup vs baseline: 2.9420x; 1.1763x over previous
//
#include <hip/hip_runtime.h>
#include <hip/hip_bf16.h>

#define H1 1024
#define FOURH 4096
#define BATCH 512
#define SEQ 64
#define DIN 128
#define TDEC 8
#define SCR 68

typedef float f32x4 __attribute__((ext_vector_type(4)));
typedef __bf16 bf16x8 __attribute__((ext_vector_type(8)));

// global->LDS direct, 16B per lane. LDS dest is wave-uniform base + lane*16.
__device__ __forceinline__ void gl_lds16(const void* g, void* l) {
    __builtin_amdgcn_global_load_lds(
        (const __attribute__((address_space(1))) unsigned int*)g,
        (__attribute__((address_space(3))) unsigned int*)l, 16, 0, 0);
}

// ---------------------------------------------------------------------------
// Weights [4096][K] f32 -> permuted interleaved-pair bf16.
// dst row dr = uc*64 + c  (uc 0..63, c 0..63; unit = uc*16 + (c>>2), gate=c&3,
// src row r = gate*1024 + unit). Row layout: K/32 blocks of 128B =
// [hi(32 elems) 64B | lo(32 elems) 64B]  -> row bytes = 4K, same as f32 row.
// ---------------------------------------------------------------------------
__global__ __launch_bounds__(256) void conv_wpair_k(
    const float* __restrict__ src, __bf16* __restrict__ dst, int K, int ks5)
{
    int i = blockIdx.x * 256 + threadIdx.x;          // piece = 8 elems
    int c  = i & 63;
    int g  = (i >> 6) & 3;
    int t  = (i >> 8) & 1;
    int kk = (i >> 9) & ((1 << ks5) - 1);
    int uc = i >> (9 + ks5);
    int r  = (c & 3) * 1024 + uc * 16 + (c >> 2);
    const float* s = src + (size_t)r * K + kk * 32 + g * 8;
    bf16x8 p;
#pragma unroll
    for (int e = 0; e < 8; ++e) {
        float v = s[e];
        __bf16 h = (__bf16)v;
        p[e] = t ? (__bf16)(v - (float)h) : h;
    }
    int dr = uc * 64 + c;
    *(bf16x8*)(dst + (size_t)dr * 2 * K + kk * 64 + t * 32 + g * 8) = p;
}

// ---------------------------------------------------------------------------
// Fused GEMM + LSTM cell, all-pair all-LDS variant.
// Block = 64 batch x 64 gate-cols (16 units). grid 512 = 8 bm x 64 uc
// (wg%8 = uc%8 -> B-sharing blocks on one XCD). 4 waves (2m x 2n), wave tile
// 32x32 (2x2 frags of 16x16x32), 3-term hi/lo MFMA. 2 blocks/CU (64KB LDS).
// A and B staged via gl_lds16 only (pure FIFO, vmcnt(8), 4 bufs, 3-deep).
// Operand rows are interleaved-pair (128B per 32-k: hi64|lo64) — byte-
// compatible with f32 rows, so layer-0's x segment stays f32 and is split
// in-register (a0f32, 4 chunks only). Cell epilogue in-block; h out as
// interleaved pair.
// ---------------------------------------------------------------------------
__global__ __launch_bounds__(256, 2) void lstm_fb2(
    const char* __restrict__ a0, long long a0row_b, int k0, int a0f32,
    const char* __restrict__ a1,                     // h pair, row 4096B
    const __bf16* __restrict__ w0p,                  // permuted pair, row 4*k0 B
    const __bf16* __restrict__ w1p,                  // permuted pair, row 4096B
    const float* __restrict__ bias,
    float* __restrict__ cst, __bf16* __restrict__ hout)
{
    __shared__ char smem[65536];                     // 4 bufs x (A 8KB + B 8KB)
    const int tid  = threadIdx.x;
    const int lane = tid & 63;
    const int w    = tid >> 6;                       // wave 0..3
    const int wm   = w >> 1, wn = w & 1;
    const int wg   = blockIdx.x;
    const int bm   = wg >> 6;                        // 0..7
    const int uc   = wg & 63;                        // 0..63

    const int nA = k0 >> 5;
    const int n  = nA + 32;

    // ---- staging geometry: 4 gl_lds16 per wave per chunk (A 2 + B 2) ----
    const int rsub = lane >> 3;
    const int slot = lane & 7;
    const int gsw  = slot ^ rsub;                    // XOR-swizzled src granule

    const char* paj0[2]; const char* paj1[2];
    const char* pbj0[2]; const char* pbj1[2];
#pragma unroll
    for (int j = 0; j < 2; ++j) {
        int ar = bm * 64 + w * 16 + j * 8 + rsub;
        paj0[j] = a0 + (size_t)ar * a0row_b + gsw * 16;
        paj1[j] = a1 + (size_t)ar * 4096 + gsw * 16;
        int c  = w * 16 + j * 8 + rsub;              // B row (gate-col)
        int dr = uc * 64 + c;
        pbj0[j] = (const char*)w0p + (size_t)dr * (4 * (size_t)k0) + gsw * 16;
        pbj1[j] = (const char*)w1p + (size_t)dr * 4096 + gsw * 16;
    }

    // LDS dests are wave-uniform (HW adds lane*16): wave w, sub-block j
    // covers LDS rows w*16+j*8 .. +8 (8 rows x 128B = 1024B per gl_lds16).
    auto stage = [&](int ii, int buf) {
        char* bufA = smem + buf * 16384;
        char* bufB = bufA + 8192;
        if (ii < nA) {
            size_t kb = (size_t)ii * 128;
#pragma unroll
            for (int j = 0; j < 2; ++j) {
                gl_lds16(paj0[j] + kb, bufA + w * 2048 + j * 1024);
                gl_lds16(pbj0[j] + kb, bufB + w * 2048 + j * 1024);
            }
        } else {
            size_t kb = (size_t)(ii - nA) * 128;
#pragma unroll
            for (int j = 0; j < 2; ++j) {
                gl_lds16(paj1[j] + kb, bufA + w * 2048 + j * 1024);
                gl_lds16(pbj1[j] + kb, bufB + w * 2048 + j * 1024);
            }
        }
    };

    // ---- fragment geometry ----
    int rA[2], rB[2];
#pragma unroll
    for (int f = 0; f < 2; ++f) {
        rA[f] = wm * 32 + f * 16 + (lane & 15);
        rB[f] = wn * 32 + f * 16 + (lane & 15);
    }
    const int s7 = lane & 7;
    const int g0 = lane >> 4;                        // k-granule group 0..3

    f32x4 acc[2][2];
#pragma unroll
    for (int a = 0; a < 2; ++a)
#pragma unroll
        for (int b = 0; b < 2; ++b)
            acc[a][b] = (f32x4){0.f, 0.f, 0.f, 0.f};

    stage(0, 0); stage(1, 1); stage(2, 2);

    for (int i = 0; i < n; ++i) {
        const int rem = n - i;
        if (rem >= 3)      asm volatile("s_waitcnt vmcnt(8)" ::: "memory");
        else if (rem == 2) asm volatile("s_waitcnt vmcnt(4)" ::: "memory");
        else               asm volatile("s_waitcnt vmcnt(0)" ::: "memory");
        __builtin_amdgcn_sched_barrier(0);
        __builtin_amdgcn_s_barrier();
        __builtin_amdgcn_sched_barrier(0);

        if (i + 3 < n) stage(i + 3, (i + 3) & 3);

        char* bufA = smem + (i & 3) * 16384;
        char* bufB = bufA + 8192;

        bf16x8 ah[2], al[2], bh[2], bl[2];
        if (a0f32 && i < nA) {                       // layer-0 x chunks only
#pragma unroll
            for (int f = 0; f < 2; ++f) {
                f32x4 v0 = *(const f32x4*)(bufA + rA[f] * 128 + ((2 * g0    ) ^ s7) * 16);
                f32x4 v1 = *(const f32x4*)(bufA + rA[f] * 128 + ((2 * g0 + 1) ^ s7) * 16);
#pragma unroll
                for (int e = 0; e < 4; ++e) {
                    __bf16 h0 = (__bf16)v0[e];
                    ah[f][e] = h0; al[f][e] = (__bf16)(v0[e] - (float)h0);
                    __bf16 h1 = (__bf16)v1[e];
                    ah[f][e + 4] = h1; al[f][e + 4] = (__bf16)(v1[e] - (float)h1);
                }
            }
        } else {
#pragma unroll
            for (int f = 0; f < 2; ++f) {
                ah[f] = *(const bf16x8*)(bufA + rA[f] * 128 + ((g0    ) ^ s7) * 16);
                al[f] = *(const bf16x8*)(bufA + rA[f] * 128 + ((g0 + 4) ^ s7) * 16);
            }
        }
#pragma unroll
        for (int f = 0; f < 2; ++f) {
            bh[f] = *(const bf16x8*)(bufB + rB[f] * 128 + ((g0    ) ^ s7) * 16);
            bl[f] = *(const bf16x8*)(bufB + rB[f] * 128 + ((g0 + 4) ^ s7) * 16);
        }
#pragma unroll
        for (int mf = 0; mf < 2; ++mf)
#pragma unroll
            for (int nf = 0; nf < 2; ++nf) {
                acc[mf][nf] = __builtin_amdgcn_mfma_f32_16x16x32_bf16(
                    ah[mf], bh[nf], acc[mf][nf], 0, 0, 0);
                acc[mf][nf] = __builtin_amdgcn_mfma_f32_16x16x32_bf16(
                    ah[mf], bl[nf], acc[mf][nf], 0, 0, 0);
                acc[mf][nf] = __builtin_amdgcn_mfma_f32_16x16x32_bf16(
                    al[mf], bh[nf], acc[mf][nf], 0, 0, 0);
            }
        __builtin_amdgcn_sched_barrier(0);
    }

    // ---- epilogue: acc -> LDS scratch [64][SCR] f32 ----
    __syncthreads();
    float* scr = (float*)smem;
#pragma unroll
    for (int mf = 0; mf < 2; ++mf)
#pragma unroll
        for (int nf = 0; nf < 2; ++nf) {
            int row0 = wm * 32 + mf * 16 + (lane >> 4) * 4;   // m89 C layout
            int col  = wn * 32 + nf * 16 + (lane & 15);
#pragma unroll
            for (int j = 0; j < 4; ++j)
                scr[(row0 + j) * SCR + col] = acc[mf][nf][j];
        }
    __syncthreads();

    // ---- in-block cell: 64 rows x 16 units ----
#pragma unroll
    for (int p = 0; p < 4; ++p) {
        int item = p * 256 + tid;
        int u = item & 15;
        int r = item >> 4;                           // 0..63
        f32x4 g4 = *(const f32x4*)(scr + r * SCR + u * 4);
        int gu = uc * 16 + u;
        float gi = g4[0] + bias[gu];
        float gf = g4[1] + bias[H1 + gu];
        float gg = g4[2] + bias[2 * H1 + gu];
        float go = g4[3] + bias[3 * H1 + gu];
        float si = 1.f / (1.f + expf(-gi));
        float sf = 1.f / (1.f + expf(-gf));
        float so = 1.f / (1.f + expf(-go));
        int row_g = bm * 64 + r;
        size_t ci = (size_t)row_g * H1 + gu;
        float cc = sf * cst[ci] + si * tanhf(gg);
        cst[ci] = cc;
        float hv = so * tanhf(cc);
        __bf16 hh = (__bf16)hv;
        size_t hb = (size_t)row_g * 2048 + (gu >> 5) * 64 + (gu & 31);
        hout[hb]      = hh;
        hout[hb + 32] = (__bf16)(hv - (float)hh);
    }
}

// head on interleaved-pair h
__global__ __launch_bounds__(256) void head_pair_k(
    const __bf16* __restrict__ hp, const float* __restrict__ W,
    const float* __restrict__ bo, float* __restrict__ out)
{
    int idx = blockIdx.x * 256 + threadIdx.x;        // 0..8191
    int b = idx >> 4, o = idx & 15;
    const __bf16* hr = hp + (size_t)b * 2048;
    const float* wr = W + (size_t)o * H1;
    float s = bo[o];
#pragma unroll 2
    for (int kb = 0; kb < 32; ++kb) {                // 32-unit blocks
#pragma unroll
        for (int q = 0; q < 4; ++q) {
            bf16x8 vh = *(const bf16x8*)(hr + kb * 64 + q * 8);
            bf16x8 vl = *(const bf16x8*)(hr + kb * 64 + 32 + q * 8);
            const f32x4* wv = (const f32x4*)(wr + kb * 32 + q * 8);
            f32x4 w0 = wv[0], w1 = wv[1];
#pragma unroll
            for (int e = 0; e < 4; ++e)
                s += ((float)vh[e] + (float)vl[e]) * w0[e];
#pragma unroll
            for (int e = 4; e < 8; ++e)
                s += ((float)vh[e] + (float)vl[e]) * w1[e - 4];
        }
    }
    out[(size_t)b * 32 + o]      = s;
    out[(size_t)b * 32 + 16 + o] = s;
}

// ---------------------------------------------------------------------------
// FALLBACK (r9/r10-proven f32 all-LDS path) — runs only if ws too small.
// ---------------------------------------------------------------------------
__global__ __launch_bounds__(256, 1) void lstm_fused_f32(
    const float* __restrict__ a0v, long long arow_b, int k0,
    const float* __restrict__ w0v,
    const float* __restrict__ a1v,
    const float* __restrict__ w1v,
    const float* __restrict__ bias,
    float* __restrict__ cst, float* __restrict__ houtv)
{
    extern __shared__ char smem[];
    const int tid  = threadIdx.x;
    const int lane = tid & 63;
    const int w    = tid >> 6;
    const int wm   = w >> 1, wn = w & 1;
    const int wg   = blockIdx.x;
    const int bm   = wg >> 5;
    const int uc   = wg & 31;

    const int nA = k0 >> 5;
    const int n  = nA + 32;

    const int rsub = lane >> 3;
    const int slot = lane & 7;
    const int gsw  = slot ^ rsub;

    const char* paj0[2]; const char* paj1[2];
    const char* pbj0[4]; const char* pbj1[4];
#pragma unroll
    for (int j = 0; j < 2; ++j) {
        int ar = bm * 64 + w * 16 + j * 8 + rsub;
        paj0[j] = (const char*)a0v + (size_t)ar * arow_b + gsw * 16;
        paj1[j] = (const char*)a1v + (size_t)ar * 4096 + gsw * 16;
    }
#pragma unroll
    for (int j = 0; j < 4; ++j) {
        int c = w * 32 + j * 8 + rsub;
        int br0 = (c & 3) * H1 + uc * 32 + (c >> 2);
        pbj0[j] = (const char*)w0v + (size_t)br0 * (4 * (size_t)k0) + gsw * 16;
        pbj1[j] = (const char*)w1v + (size_t)br0 * 4096 + gsw * 16;
    }

    auto stage = [&](int ii, int buf) {
        char* bufA = smem + buf * 24576;
        char* bufB = bufA + 8192;
        size_t kb = (ii < nA) ? (size_t)ii * 128 : (size_t)(ii - nA) * 128;
        const char* const* pa = (ii < nA) ? paj0 : paj1;
        const char* const* pb = (ii < nA) ? pbj0 : pbj1;
#pragma unroll
        for (int j = 0; j < 2; ++j)
            gl_lds16(pa[j] + kb, bufA + (w * 2 + j) * 1024);
#pragma unroll
        for (int j = 0; j < 4; ++j)
            gl_lds16(pb[j] + kb, bufB + (w * 4 + j) * 1024);
    };

    int rAv[2], rBv[4];
#pragma unroll
    for (int f = 0; f < 2; ++f) rAv[f] = wm * 32 + f * 16 + (lane & 15);
#pragma unroll
    for (int f = 0; f < 4; ++f) rBv[f] = wn * 64 + f * 16 + (lane & 15);
    const int s7 = lane & 7;
    const int g0 = lane >> 4;

    f32x4 acc[2][4];
#pragma unroll
    for (int mf = 0; mf < 2; ++mf)
#pragma unroll
        for (int nf = 0; nf < 4; ++nf)
            acc[mf][nf] = (f32x4){0.f, 0.f, 0.f, 0.f};

    stage(0, 0); stage(1, 1); stage(2, 2); stage(3, 3); stage(4, 4);

    int buf = 0;
    for (int i = 0; i < n; ++i) {
        const int rem = n - i;
        if (rem >= 5)      asm volatile("s_waitcnt vmcnt(24)" ::: "memory");
        else if (rem == 4) asm volatile("s_waitcnt vmcnt(18)" ::: "memory");
        else if (rem == 3) asm volatile("s_waitcnt vmcnt(12)" ::: "memory");
        else if (rem == 2) asm volatile("s_waitcnt vmcnt(6)"  ::: "memory");
        else               asm volatile("s_waitcnt vmcnt(0)"  ::: "memory");
        __builtin_amdgcn_sched_barrier(0);
        __builtin_amdgcn_s_barrier();
        __builtin_amdgcn_sched_barrier(0);

        if (i + 5 < n) {
            int b5 = buf + 5; if (b5 >= 6) b5 -= 6;
            stage(i + 5, b5);
        }

        char* bufA = smem + buf * 24576;
        char* bufB = bufA + 8192;

        bf16x8 ah[2], al[2], bh[4], bl[4];
#pragma unroll
        for (int f = 0; f < 2; ++f) {
            f32x4 v0 = *(const f32x4*)(bufA + rAv[f] * 128 + ((2 * g0    ) ^ s7) * 16);
            f32x4 v1 = *(const f32x4*)(bufA + rAv[f] * 128 + ((2 * g0 + 1) ^ s7) * 16);
#pragma unroll
            for (int e = 0; e < 4; ++e) {
                __bf16 h0 = (__bf16)v0[e];
                ah[f][e] = h0; al[f][e] = (__bf16)(v0[e] - (float)h0);
                __bf16 h1 = (__bf16)v1[e];
                ah[f][e + 4] = h1; al[f][e + 4] = (__bf16)(v1[e] - (float)h1);
            }
        }
#pragma unroll
        for (int f = 0; f < 4; ++f) {
            f32x4 u0 = *(const f32x4*)(bufB + rBv[f] * 128 + ((2 * g0    ) ^ s7) * 16);
            f32x4 u1 = *(const f32x4*)(bufB + rBv[f] * 128 + ((2 * g0 + 1) ^ s7) * 16);
#pragma unroll
            for (int e = 0; e < 4; ++e) {
                __bf16 h0 = (__bf16)u0[e];
                bh[f][e] = h0; bl[f][e] = (__bf16)(u0[e] - (float)h0);
                __bf16 h1 = (__bf16)u1[e];
                bh[f][e + 4] = h1; bl[f][e + 4] = (__bf16)(u1[e] - (float)h1);
            }
        }
#pragma unroll
        for (int mf = 0; mf < 2; ++mf)
#pragma unroll
            for (int nf = 0; nf < 4; ++nf) {
                acc[mf][nf] = __builtin_amdgcn_mfma_f32_16x16x32_bf16(
                    ah[mf], bh[nf], acc[mf][nf], 0, 0, 0);
                acc[mf][nf] = __builtin_amdgcn_mfma_f32_16x16x32_bf16(
                    ah[mf], bl[nf], acc[mf][nf], 0, 0, 0);
                acc[mf][nf] = __builtin_amdgcn_mfma_f32_16x16x32_bf16(
                    al[mf], bh[nf], acc[mf][nf], 0, 0, 0);
            }
        __builtin_amdgcn_sched_barrier(0);
        buf = buf + 1; if (buf >= 6) buf -= 6;
    }

    __syncthreads();
    float* scr = (float*)smem;
#pragma unroll
    for (int mf = 0; mf < 2; ++mf)
#pragma unroll
        for (int nf = 0; nf < 4; ++nf) {
            int row0 = wm * 32 + mf * 16 + (lane >> 4) * 4;
            int col  = wn * 64 + nf * 16 + (lane & 15);
#pragma unroll
            for (int j = 0; j < 4; ++j)
                scr[(row0 + j) * 128 + col] = acc[mf][nf][j];
        }
    __syncthreads();

#pragma unroll
    for (int p = 0; p < 8; ++p) {
        int item = p * 256 + tid;
        int u = item & 31;
        int r = item >> 5;
        f32x4 g4 = *(const f32x4*)(scr + r * 128 + u * 4);
        int gu = uc * 32 + u;
        float gi = g4[0] + bias[gu];
        float gf = g4[1] + bias[H1 + gu];
        float gg = g4[2] + bias[2 * H1 + gu];
        float go = g4[3] + bias[3 * H1 + gu];
        float si = 1.f / (1.f + expf(-gi));
        float sf = 1.f / (1.f + expf(-gf));
        float so = 1.f / (1.f + expf(-go));
        size_t ci = (size_t)(bm * 64 + r) * H1 + gu;
        float cc = sf * cst[ci] + si * tanhf(gg);
        cst[ci] = cc;
        houtv[ci] = so * tanhf(cc);
    }
}

__global__ __launch_bounds__(256) void head_k(
    const float* __restrict__ h, const float* __restrict__ W,
    const float* __restrict__ bo, float* __restrict__ out)
{
    int idx = blockIdx.x * 256 + threadIdx.x;
    int b = idx >> 4, o = idx & 15;
    const f32x4* hv = (const f32x4*)(h + (size_t)b * H1);
    const f32x4* wv = (const f32x4*)(W + (size_t)o * H1);
    float s = bo[o];
#pragma unroll 4
    for (int k = 0; k < H1 / 4; ++k) {
        f32x4 a = hv[k];
        f32x4 wq = wv[k];
        s += a[0] * wq[0] + a[1] * wq[1] + a[2] * wq[2] + a[3] * wq[3];
    }
    out[(size_t)b * 32 + o]      = s;
    out[(size_t)b * 32 + 16 + o] = s;
}

// ===========================================================================
extern "C" void kernel_launch(void* const* d_in, const int* in_sizes, int n_in,
                              void* d_out, int out_size, void* d_ws, size_t ws_size,
                              hipStream_t stream)
{
    const float* x    = (const float*)d_in[0];
    const float* Wih0 = (const float*)d_in[1];
    const float* Whh0 = (const float*)d_in[2];
    const float* b0   = (const float*)d_in[3];
    const float* Wih1 = (const float*)d_in[4];
    const float* Whh1 = (const float*)d_in[5];
    const float* b1   = (const float*)d_in[6];
    const float* dWih = (const float*)d_in[7];
    const float* dWhh = (const float*)d_in[8];
    const float* db   = (const float*)d_in[9];
    const float* Wout = (const float*)d_in[10];
    const float* bout = (const float*)d_in[11];

    dim3 blk(256);
    const size_t WP_SMALL = (size_t)4096 * 128 * 4;    // 2MB   (K=128 pair)
    const size_t WP_BIG   = (size_t)4096 * 1024 * 4;   // 16MB  (K=1024 pair)
    const size_t HPB      = (size_t)BATCH * 4096;      // 2MB   h pair bytes
    const size_t CSZ      = (size_t)BATCH * H1;        // elems
    const size_t NEED1    = WP_SMALL + 7 * WP_BIG + 4 * HPB + 2 * CSZ * 4;

    const float* dWih1 = dWih + (size_t)FOURH * H1;
    const float* dWhh1 = dWhh + (size_t)FOURH * H1;

    if (ws_size >= NEED1) {
        // ---------------- pair path ----------------
        char* wsb = (char*)d_ws;
        __bf16* Wih0p  = (__bf16*)wsb;
        __bf16* Whh0p  = (__bf16*)(wsb + WP_SMALL);
        __bf16* Wih1p  = (__bf16*)(wsb + WP_SMALL + WP_BIG);
        __bf16* Whh1p  = (__bf16*)(wsb + WP_SMALL + 2 * WP_BIG);
        __bf16* dWih0p = (__bf16*)(wsb + WP_SMALL + 3 * WP_BIG);
        __bf16* dWhh0p = (__bf16*)(wsb + WP_SMALL + 4 * WP_BIG);
        __bf16* dWih1p = (__bf16*)(wsb + WP_SMALL + 5 * WP_BIG);
        __bf16* dWhh1p = (__bf16*)(wsb + WP_SMALL + 6 * WP_BIG);
        char* sb = wsb + WP_SMALL + 7 * WP_BIG;
        __bf16* hp0a = (__bf16*)sb;
        __bf16* hp0b = (__bf16*)(sb + HPB);
        __bf16* hp1a = (__bf16*)(sb + 2 * HPB);
        __bf16* hp1b = (__bf16*)(sb + 3 * HPB);
        float*  c0   = (float*)(sb + 4 * HPB);
        float*  c1   = c0 + CSZ;

        auto convw = [&](const float* s, __bf16* d, int K, int ks5) {
            int total = 32768 * (K >> 5);
            conv_wpair_k<<<dim3(total / 256), blk, 0, stream>>>(s, d, K, ks5);
        };
        convw(Wih0, Wih0p, 128, 2);
        convw(Whh0, Whh0p, 1024, 5);
        convw(Wih1, Wih1p, 1024, 5);
        convw(Whh1, Whh1p, 1024, 5);
        convw(dWih,  dWih0p, 1024, 5);
        convw(dWih1, dWih1p, 1024, 5);
        convw(dWhh,  dWhh0p, 1024, 5);
        convw(dWhh1, dWhh1p, 1024, 5);

        hipMemsetAsync(sb, 0, 4 * HPB + 2 * CSZ * 4, stream);

        dim3 fgrid(512);
        __bf16 *hc = hp0a, *hn = hp0b, *h1c = hp1a, *h1n = hp1b;
        const long long XROW = (long long)(SEQ * DIN * 4);
        for (int t = 0; t < SEQ; ++t) {
            lstm_fb2<<<fgrid, blk, 0, stream>>>(
                (const char*)(x + (size_t)t * DIN), XROW, DIN, 1,
                (const char*)hc, Wih0p, Whh0p, b0, c0, hn);
            lstm_fb2<<<fgrid, blk, 0, stream>>>(
                (const char*)hn, 4096LL, H1, 0,
                (const char*)h1c, Wih1p, Whh1p, b1, c1, h1n);
            __bf16* t0 = hc; hc = hn; hn = t0;
            __bf16* t1 = h1c; h1c = h1n; h1n = t1;
        }
        for (int s = 0; s < TDEC; ++s) {
            lstm_fb2<<<fgrid, blk, 0, stream>>>(
                (const char*)h1c, 4096LL, H1, 0,
                (const char*)hc, dWih0p, dWhh0p, db, c0, hn);
            lstm_fb2<<<fgrid, blk, 0, stream>>>(
                (const char*)hn, 4096LL, H1, 0,
                (const char*)h1c, dWih1p, dWhh1p, db + FOURH, c1, h1n);
            __bf16* t0 = hc; hc = hn; hn = t0;
            __bf16* t1 = h1c; h1c = h1n; h1n = t1;
        }
        head_pair_k<<<dim3(32), blk, 0, stream>>>(h1c, Wout, bout, (float*)d_out);
    } else {
        // ---------------- f32 fallback (proven) ----------------
        float* h0a = (float*)d_ws;
        float* h0b = h0a + CSZ;
        float* h1a = h0b + CSZ;
        float* h1b = h1a + CSZ;
        float* c0  = h1b + CSZ;
        float* c1  = c0 + CSZ;
        hipMemsetAsync(h0a, 0, 6 * CSZ * 4, stream);

        (void)hipFuncSetAttribute(reinterpret_cast<const void*>(&lstm_fused_f32),
                                  hipFuncAttributeMaxDynamicSharedMemorySize, 147456);

        dim3 oldgrid(256);
        float *hc = h0a, *hn = h0b, *h1c = h1a, *h1n = h1b;
        for (int t = 0; t < SEQ; ++t) {
            lstm_fused_f32<<<oldgrid, blk, 147456, stream>>>(
                x + (size_t)t * DIN, (long long)(SEQ * DIN * 4), DIN, Wih0,
                hc, Whh0, b0, c0, hn);
            lstm_fused_f32<<<oldgrid, blk, 147456, stream>>>(
                hn, 4096LL, H1, Wih1, h1c, Whh1, b1, c1, h1n);
            float* t0 = hc; hc = hn; hn = t0;
            float* t1 = h1c; h1c = h1n; h1n = t1;
        }
        for (int s = 0; s < TDEC; ++s) {
            lstm_fused_f32<<<oldgrid, blk, 147456, stream>>>(
                h1c, 4096LL, H1, dWih, hc, dWhh, db, c0, hn);
            lstm_fused_f32<<<oldgrid, blk, 147456, stream>>>(
                hn, 4096LL, H1, dWih1, h1c, dWhh1, db + FOURH, c1, h1n);
            float* t0 = hc; hc = hn; hn = t0;
            float* t1 = h1c; h1c = h1n; h1n = t1;
        }
        head_k<<<dim3(32), blk, 0, stream>>>(h1c, Wout, bout, (float*)d_out);
    }
}

// Round 14
// 4184.380 us; speedup vs baseline: 3.0587x; 1.0397x over previous
//
#include <hip/hip_runtime.h>
#include <hip/hip_bf16.h>

#define H1 1024
#define FOURH 4096
#define BATCH 512
#define SEQ 64
#define DIN 128
#define TDEC 8
#define SCR 68

typedef float f32x4 __attribute__((ext_vector_type(4)));
typedef __bf16 bf16x8 __attribute__((ext_vector_type(8)));

// global->LDS direct, 16B per lane. LDS dest is wave-uniform base + lane*16.
__device__ __forceinline__ void gl_lds16(const void* g, void* l) {
    __builtin_amdgcn_global_load_lds(
        (const __attribute__((address_space(1))) unsigned int*)g,
        (__attribute__((address_space(3))) unsigned int*)l, 16, 0, 0);
}

// ---------------------------------------------------------------------------
// Weights [4096][K] f32 -> permuted interleaved-pair bf16.
// dst row dr = uc*64 + c  (uc 0..63, c 0..63; unit = uc*16 + (c>>2), gate=c&3,
// src row r = gate*1024 + unit). Row layout: K/32 blocks of 128B =
// [hi(32 elems) 64B | lo(32 elems) 64B]  -> row bytes = 4K, same as f32 row.
// ---------------------------------------------------------------------------
__global__ __launch_bounds__(256) void conv_wpair_k(
    const float* __restrict__ src, __bf16* __restrict__ dst, int K, int ks5)
{
    int i = blockIdx.x * 256 + threadIdx.x;          // piece = 8 elems
    int c  = i & 63;
    int g  = (i >> 6) & 3;
    int t  = (i >> 8) & 1;
    int kk = (i >> 9) & ((1 << ks5) - 1);
    int uc = i >> (9 + ks5);
    int r  = (c & 3) * 1024 + uc * 16 + (c >> 2);
    const float* s = src + (size_t)r * K + kk * 32 + g * 8;
    bf16x8 p;
#pragma unroll
    for (int e = 0; e < 8; ++e) {
        float v = s[e];
        __bf16 h = (__bf16)v;
        p[e] = t ? (__bf16)(v - (float)h) : h;
    }
    int dr = uc * 64 + c;
    *(bf16x8*)(dst + (size_t)dr * 2 * K + kk * 64 + t * 32 + g * 8) = p;
}

// ---------------------------------------------------------------------------
// Fused GEMM + LSTM cell, all-pair all-LDS variant.
// Block = 64 batch x 64 gate-cols (16 units). grid 512 = 8 bm x 64 uc
// (wg%8 = uc%8 -> B-sharing blocks on one XCD). 4 waves (2m x 2n), wave tile
// 32x32 (2x2 frags of 16x16x32), 3-term hi/lo MFMA. 2 blocks/CU (64KB LDS).
// A and B staged via gl_lds16 only (pure FIFO). Barrier every TWO chunks:
// interval = {vmcnt(0) (pre-satisfied), barrier, stage i+2/i+3 into bufs
// freed last interval, compute i and i+1}. Halves barrier/convoy count.
// Operand rows are interleaved-pair (128B per 32-k: hi64|lo64) — byte-
// compatible with f32 rows, so layer-0's x segment stays f32 and is split
// in-register (a0f32, 4 chunks only). Cell epilogue in-block; h out as
// interleaved pair.
// ---------------------------------------------------------------------------
__global__ __launch_bounds__(256, 2) void lstm_fb2(
    const char* __restrict__ a0, long long a0row_b, int k0, int a0f32,
    const char* __restrict__ a1,                     // h pair, row 4096B
    const __bf16* __restrict__ w0p,                  // permuted pair, row 4*k0 B
    const __bf16* __restrict__ w1p,                  // permuted pair, row 4096B
    const float* __restrict__ bias,
    float* __restrict__ cst, __bf16* __restrict__ hout)
{
    __shared__ char smem[65536];                     // 4 bufs x (A 8KB + B 8KB)
    const int tid  = threadIdx.x;
    const int lane = tid & 63;
    const int w    = tid >> 6;                       // wave 0..3
    const int wm   = w >> 1, wn = w & 1;
    const int wg   = blockIdx.x;
    const int bm   = wg >> 6;                        // 0..7
    const int uc   = wg & 63;                        // 0..63

    const int nA = k0 >> 5;
    const int n  = nA + 32;                          // even for all layers

    // ---- staging geometry: 4 gl_lds16 per wave per chunk (A 2 + B 2) ----
    const int rsub = lane >> 3;
    const int slot = lane & 7;
    const int gsw  = slot ^ rsub;                    // XOR-swizzled src granule

    const char* paj0[2]; const char* paj1[2];
    const char* pbj0[2]; const char* pbj1[2];
#pragma unroll
    for (int j = 0; j < 2; ++j) {
        int ar = bm * 64 + w * 16 + j * 8 + rsub;
        paj0[j] = a0 + (size_t)ar * a0row_b + gsw * 16;
        paj1[j] = a1 + (size_t)ar * 4096 + gsw * 16;
        int c  = w * 16 + j * 8 + rsub;              // B row (gate-col)
        int dr = uc * 64 + c;
        pbj0[j] = (const char*)w0p + (size_t)dr * (4 * (size_t)k0) + gsw * 16;
        pbj1[j] = (const char*)w1p + (size_t)dr * 4096 + gsw * 16;
    }

    // LDS dests are wave-uniform (HW adds lane*16): wave w, sub-block j
    // covers LDS rows w*16+j*8 .. +8 (8 rows x 128B = 1024B per gl_lds16).
    auto stage = [&](int ii, int buf) {
        char* bufA = smem + buf * 16384;
        char* bufB = bufA + 8192;
        if (ii < nA) {
            size_t kb = (size_t)ii * 128;
#pragma unroll
            for (int j = 0; j < 2; ++j) {
                gl_lds16(paj0[j] + kb, bufA + w * 2048 + j * 1024);
                gl_lds16(pbj0[j] + kb, bufB + w * 2048 + j * 1024);
            }
        } else {
            size_t kb = (size_t)(ii - nA) * 128;
#pragma unroll
            for (int j = 0; j < 2; ++j) {
                gl_lds16(paj1[j] + kb, bufA + w * 2048 + j * 1024);
                gl_lds16(pbj1[j] + kb, bufB + w * 2048 + j * 1024);
            }
        }
    };

    // ---- fragment geometry ----
    int rA[2], rB[2];
#pragma unroll
    for (int f = 0; f < 2; ++f) {
        rA[f] = wm * 32 + f * 16 + (lane & 15);
        rB[f] = wn * 32 + f * 16 + (lane & 15);
    }
    const int s7 = lane & 7;
    const int g0 = lane >> 4;                        // k-granule group 0..3

    f32x4 acc[2][2];
#pragma unroll
    for (int a = 0; a < 2; ++a)
#pragma unroll
        for (int b = 0; b < 2; ++b)
            acc[a][b] = (f32x4){0.f, 0.f, 0.f, 0.f};

    auto chunk = [&](int i) {
        char* bufA = smem + (i & 3) * 16384;
        char* bufB = bufA + 8192;
        bf16x8 ah[2], al[2], bh[2], bl[2];
        if (a0f32 && i < nA) {                       // layer-0 x chunks only
#pragma unroll
            for (int f = 0; f < 2; ++f) {
                f32x4 v0 = *(const f32x4*)(bufA + rA[f] * 128 + ((2 * g0    ) ^ s7) * 16);
                f32x4 v1 = *(const f32x4*)(bufA + rA[f] * 128 + ((2 * g0 + 1) ^ s7) * 16);
#pragma unroll
                for (int e = 0; e < 4; ++e) {
                    __bf16 h0 = (__bf16)v0[e];
                    ah[f][e] = h0; al[f][e] = (__bf16)(v0[e] - (float)h0);
                    __bf16 h1 = (__bf16)v1[e];
                    ah[f][e + 4] = h1; al[f][e + 4] = (__bf16)(v1[e] - (float)h1);
                }
            }
        } else {
#pragma unroll
            for (int f = 0; f < 2; ++f) {
                ah[f] = *(const bf16x8*)(bufA + rA[f] * 128 + ((g0    ) ^ s7) * 16);
                al[f] = *(const bf16x8*)(bufA + rA[f] * 128 + ((g0 + 4) ^ s7) * 16);
            }
        }
#pragma unroll
        for (int f = 0; f < 2; ++f) {
            bh[f] = *(const bf16x8*)(bufB + rB[f] * 128 + ((g0    ) ^ s7) * 16);
            bl[f] = *(const bf16x8*)(bufB + rB[f] * 128 + ((g0 + 4) ^ s7) * 16);
        }
#pragma unroll
        for (int mf = 0; mf < 2; ++mf)
#pragma unroll
            for (int nf = 0; nf < 2; ++nf) {
                acc[mf][nf] = __builtin_amdgcn_mfma_f32_16x16x32_bf16(
                    ah[mf], bh[nf], acc[mf][nf], 0, 0, 0);
                acc[mf][nf] = __builtin_amdgcn_mfma_f32_16x16x32_bf16(
                    ah[mf], bl[nf], acc[mf][nf], 0, 0, 0);
                acc[mf][nf] = __builtin_amdgcn_mfma_f32_16x16x32_bf16(
                    al[mf], bh[nf], acc[mf][nf], 0, 0, 0);
            }
    };

    stage(0, 0); stage(1, 1);

    for (int i = 0; i < n; i += 2) {
        asm volatile("s_waitcnt vmcnt(0)" ::: "memory");
        __builtin_amdgcn_sched_barrier(0);
        __builtin_amdgcn_s_barrier();
        __builtin_amdgcn_sched_barrier(0);

        if (i + 2 < n) {                             // bufs freed last interval
            stage(i + 2, (i + 2) & 3);
            stage(i + 3, (i + 3) & 3);
        }

        chunk(i);
        chunk(i + 1);
        __builtin_amdgcn_sched_barrier(0);
    }

    // ---- epilogue: acc -> LDS scratch [64][SCR] f32 ----
    __syncthreads();
    float* scr = (float*)smem;
#pragma unroll
    for (int mf = 0; mf < 2; ++mf)
#pragma unroll
        for (int nf = 0; nf < 2; ++nf) {
            int row0 = wm * 32 + mf * 16 + (lane >> 4) * 4;   // m89 C layout
            int col  = wn * 32 + nf * 16 + (lane & 15);
#pragma unroll
            for (int j = 0; j < 4; ++j)
                scr[(row0 + j) * SCR + col] = acc[mf][nf][j];
        }
    __syncthreads();

    // ---- in-block cell: 64 rows x 16 units ----
#pragma unroll
    for (int p = 0; p < 4; ++p) {
        int item = p * 256 + tid;
        int u = item & 15;
        int r = item >> 4;                           // 0..63
        f32x4 g4 = *(const f32x4*)(scr + r * SCR + u * 4);
        int gu = uc * 16 + u;
        float gi = g4[0] + bias[gu];
        float gf = g4[1] + bias[H1 + gu];
        float gg = g4[2] + bias[2 * H1 + gu];
        float go = g4[3] + bias[3 * H1 + gu];
        float si = 1.f / (1.f + expf(-gi));
        float sf = 1.f / (1.f + expf(-gf));
        float so = 1.f / (1.f + expf(-go));
        int row_g = bm * 64 + r;
        size_t ci = (size_t)row_g * H1 + gu;
        float cc = sf * cst[ci] + si * tanhf(gg);
        cst[ci] = cc;
        float hv = so * tanhf(cc);
        __bf16 hh = (__bf16)hv;
        size_t hb = (size_t)row_g * 2048 + (gu >> 5) * 64 + (gu & 31);
        hout[hb]      = hh;
        hout[hb + 32] = (__bf16)(hv - (float)hh);
    }
}

// ---------------------------------------------------------------------------
// head on interleaved-pair h — wave-parallel: 16 lanes per output, shfl_xor
// reduce. grid 512 x 256 threads = 16 outputs/block.
// ---------------------------------------------------------------------------
__global__ __launch_bounds__(256) void head_pair2_k(
    const __bf16* __restrict__ hp, const float* __restrict__ W,
    const float* __restrict__ bo, float* __restrict__ out)
{
    int gid  = blockIdx.x * 16 + (threadIdx.x >> 4); // output 0..8191
    int l16  = threadIdx.x & 15;
    int b = gid >> 4, o = gid & 15;
    const __bf16* hr = hp + (size_t)b * 2048 + l16 * 128;  // 2 unit-blocks
    const float*  wr = W + (size_t)o * H1 + l16 * 64;
    float s = 0.f;
#pragma unroll
    for (int q = 0; q < 2; ++q) {
#pragma unroll
        for (int r = 0; r < 4; ++r) {
            bf16x8 vh = *(const bf16x8*)(hr + q * 64 + r * 8);
            bf16x8 vl = *(const bf16x8*)(hr + q * 64 + 32 + r * 8);
            const f32x4* wv = (const f32x4*)(wr + q * 32 + r * 8);
            f32x4 w0 = wv[0], w1 = wv[1];
#pragma unroll
            for (int e = 0; e < 4; ++e)
                s += ((float)vh[e] + (float)vl[e]) * w0[e];
#pragma unroll
            for (int e = 4; e < 8; ++e)
                s += ((float)vh[e] + (float)vl[e]) * w1[e - 4];
        }
    }
#pragma unroll
    for (int m = 8; m >= 1; m >>= 1)
        s += __shfl_xor(s, m, 16);
    if (l16 == 0) {
        float v = s + bo[o];
        out[(size_t)b * 32 + o]      = v;
        out[(size_t)b * 32 + 16 + o] = v;
    }
}

// ---------------------------------------------------------------------------
// FALLBACK (r9/r10-proven f32 all-LDS path) — runs only if ws too small.
// ---------------------------------------------------------------------------
__global__ __launch_bounds__(256, 1) void lstm_fused_f32(
    const float* __restrict__ a0v, long long arow_b, int k0,
    const float* __restrict__ w0v,
    const float* __restrict__ a1v,
    const float* __restrict__ w1v,
    const float* __restrict__ bias,
    float* __restrict__ cst, float* __restrict__ houtv)
{
    extern __shared__ char smem[];
    const int tid  = threadIdx.x;
    const int lane = tid & 63;
    const int w    = tid >> 6;
    const int wm   = w >> 1, wn = w & 1;
    const int wg   = blockIdx.x;
    const int bm   = wg >> 5;
    const int uc   = wg & 31;

    const int nA = k0 >> 5;
    const int n  = nA + 32;

    const int rsub = lane >> 3;
    const int slot = lane & 7;
    const int gsw  = slot ^ rsub;

    const char* paj0[2]; const char* paj1[2];
    const char* pbj0[4]; const char* pbj1[4];
#pragma unroll
    for (int j = 0; j < 2; ++j) {
        int ar = bm * 64 + w * 16 + j * 8 + rsub;
        paj0[j] = (const char*)a0v + (size_t)ar * arow_b + gsw * 16;
        paj1[j] = (const char*)a1v + (size_t)ar * 4096 + gsw * 16;
    }
#pragma unroll
    for (int j = 0; j < 4; ++j) {
        int c = w * 32 + j * 8 + rsub;
        int br0 = (c & 3) * H1 + uc * 32 + (c >> 2);
        pbj0[j] = (const char*)w0v + (size_t)br0 * (4 * (size_t)k0) + gsw * 16;
        pbj1[j] = (const char*)w1v + (size_t)br0 * 4096 + gsw * 16;
    }

    auto stage = [&](int ii, int buf) {
        char* bufA = smem + buf * 24576;
        char* bufB = bufA + 8192;
        size_t kb = (ii < nA) ? (size_t)ii * 128 : (size_t)(ii - nA) * 128;
        const char* const* pa = (ii < nA) ? paj0 : paj1;
        const char* const* pb = (ii < nA) ? pbj0 : pbj1;
#pragma unroll
        for (int j = 0; j < 2; ++j)
            gl_lds16(pa[j] + kb, bufA + (w * 2 + j) * 1024);
#pragma unroll
        for (int j = 0; j < 4; ++j)
            gl_lds16(pb[j] + kb, bufB + (w * 4 + j) * 1024);
    };

    int rAv[2], rBv[4];
#pragma unroll
    for (int f = 0; f < 2; ++f) rAv[f] = wm * 32 + f * 16 + (lane & 15);
#pragma unroll
    for (int f = 0; f < 4; ++f) rBv[f] = wn * 64 + f * 16 + (lane & 15);
    const int s7 = lane & 7;
    const int g0 = lane >> 4;

    f32x4 acc[2][4];
#pragma unroll
    for (int mf = 0; mf < 2; ++mf)
#pragma unroll
        for (int nf = 0; nf < 4; ++nf)
            acc[mf][nf] = (f32x4){0.f, 0.f, 0.f, 0.f};

    stage(0, 0); stage(1, 1); stage(2, 2); stage(3, 3); stage(4, 4);

    int buf = 0;
    for (int i = 0; i < n; ++i) {
        const int rem = n - i;
        if (rem >= 5)      asm volatile("s_waitcnt vmcnt(24)" ::: "memory");
        else if (rem == 4) asm volatile("s_waitcnt vmcnt(18)" ::: "memory");
        else if (rem == 3) asm volatile("s_waitcnt vmcnt(12)" ::: "memory");
        else if (rem == 2) asm volatile("s_waitcnt vmcnt(6)"  ::: "memory");
        else               asm volatile("s_waitcnt vmcnt(0)"  ::: "memory");
        __builtin_amdgcn_sched_barrier(0);
        __builtin_amdgcn_s_barrier();
        __builtin_amdgcn_sched_barrier(0);

        if (i + 5 < n) {
            int b5 = buf + 5; if (b5 >= 6) b5 -= 6;
            stage(i + 5, b5);
        }

        char* bufA = smem + buf * 24576;
        char* bufB = bufA + 8192;

        bf16x8 ah[2], al[2], bh[4], bl[4];
#pragma unroll
        for (int f = 0; f < 2; ++f) {
            f32x4 v0 = *(const f32x4*)(bufA + rAv[f] * 128 + ((2 * g0    ) ^ s7) * 16);
            f32x4 v1 = *(const f32x4*)(bufA + rAv[f] * 128 + ((2 * g0 + 1) ^ s7) * 16);
#pragma unroll
            for (int e = 0; e < 4; ++e) {
                __bf16 h0 = (__bf16)v0[e];
                ah[f][e] = h0; al[f][e] = (__bf16)(v0[e] - (float)h0);
                __bf16 h1 = (__bf16)v1[e];
                ah[f][e + 4] = h1; al[f][e + 4] = (__bf16)(v1[e] - (float)h1);
            }
        }
#pragma unroll
        for (int f = 0; f < 4; ++f) {
            f32x4 u0 = *(const f32x4*)(bufB + rBv[f] * 128 + ((2 * g0    ) ^ s7) * 16);
            f32x4 u1 = *(const f32x4*)(bufB + rBv[f] * 128 + ((2 * g0 + 1) ^ s7) * 16);
#pragma unroll
            for (int e = 0; e < 4; ++e) {
                __bf16 h0 = (__bf16)u0[e];
                bh[f][e] = h0; bl[f][e] = (__bf16)(u0[e] - (float)h0);
                __bf16 h1 = (__bf16)u1[e];
                bh[f][e + 4] = h1; bl[f][e + 4] = (__bf16)(u1[e] - (float)h1);
            }
        }
#pragma unroll
        for (int mf = 0; mf < 2; ++mf)
#pragma unroll
            for (int nf = 0; nf < 4; ++nf) {
                acc[mf][nf] = __builtin_amdgcn_mfma_f32_16x16x32_bf16(
                    ah[mf], bh[nf], acc[mf][nf], 0, 0, 0);
                acc[mf][nf] = __builtin_amdgcn_mfma_f32_16x16x32_bf16(
                    ah[mf], bl[nf], acc[mf][nf], 0, 0, 0);
                acc[mf][nf] = __builtin_amdgcn_mfma_f32_16x16x32_bf16(
                    al[mf], bh[nf], acc[mf][nf], 0, 0, 0);
            }
        __builtin_amdgcn_sched_barrier(0);
        buf = buf + 1; if (buf >= 6) buf -= 6;
    }

    __syncthreads();
    float* scr = (float*)smem;
#pragma unroll
    for (int mf = 0; mf < 2; ++mf)
#pragma unroll
        for (int nf = 0; nf < 4; ++nf) {
            int row0 = wm * 32 + mf * 16 + (lane >> 4) * 4;
            int col  = wn * 64 + nf * 16 + (lane & 15);
#pragma unroll
            for (int j = 0; j < 4; ++j)
                scr[(row0 + j) * 128 + col] = acc[mf][nf][j];
        }
    __syncthreads();

#pragma unroll
    for (int p = 0; p < 8; ++p) {
        int item = p * 256 + tid;
        int u = item & 31;
        int r = item >> 5;
        f32x4 g4 = *(const f32x4*)(scr + r * 128 + u * 4);
        int gu = uc * 32 + u;
        float gi = g4[0] + bias[gu];
        float gf = g4[1] + bias[H1 + gu];
        float gg = g4[2] + bias[2 * H1 + gu];
        float go = g4[3] + bias[3 * H1 + gu];
        float si = 1.f / (1.f + expf(-gi));
        float sf = 1.f / (1.f + expf(-gf));
        float so = 1.f / (1.f + expf(-go));
        size_t ci = (size_t)(bm * 64 + r) * H1 + gu;
        float cc = sf * cst[ci] + si * tanhf(gg);
        cst[ci] = cc;
        houtv[ci] = so * tanhf(cc);
    }
}

__global__ __launch_bounds__(256) void head_k(
    const float* __restrict__ h, const float* __restrict__ W,
    const float* __restrict__ bo, float* __restrict__ out)
{
    int idx = blockIdx.x * 256 + threadIdx.x;
    int b = idx >> 4, o = idx & 15;
    const f32x4* hv = (const f32x4*)(h + (size_t)b * H1);
    const f32x4* wv = (const f32x4*)(W + (size_t)o * H1);
    float s = bo[o];
#pragma unroll 4
    for (int k = 0; k < H1 / 4; ++k) {
        f32x4 a = hv[k];
        f32x4 wq = wv[k];
        s += a[0] * wq[0] + a[1] * wq[1] + a[2] * wq[2] + a[3] * wq[3];
    }
    out[(size_t)b * 32 + o]      = s;
    out[(size_t)b * 32 + 16 + o] = s;
}

// ===========================================================================
extern "C" void kernel_launch(void* const* d_in, const int* in_sizes, int n_in,
                              void* d_out, int out_size, void* d_ws, size_t ws_size,
                              hipStream_t stream)
{
    const float* x    = (const float*)d_in[0];
    const float* Wih0 = (const float*)d_in[1];
    const float* Whh0 = (const float*)d_in[2];
    const float* b0   = (const float*)d_in[3];
    const float* Wih1 = (const float*)d_in[4];
    const float* Whh1 = (const float*)d_in[5];
    const float* b1   = (const float*)d_in[6];
    const float* dWih = (const float*)d_in[7];
    const float* dWhh = (const float*)d_in[8];
    const float* db   = (const float*)d_in[9];
    const float* Wout = (const float*)d_in[10];
    const float* bout = (const float*)d_in[11];

    dim3 blk(256);
    const size_t WP_SMALL = (size_t)4096 * 128 * 4;    // 2MB   (K=128 pair)
    const size_t WP_BIG   = (size_t)4096 * 1024 * 4;   // 16MB  (K=1024 pair)
    const size_t HPB      = (size_t)BATCH * 4096;      // 2MB   h pair bytes
    const size_t CSZ      = (size_t)BATCH * H1;        // elems
    const size_t NEED1    = WP_SMALL + 7 * WP_BIG + 4 * HPB + 2 * CSZ * 4;

    const float* dWih1 = dWih + (size_t)FOURH * H1;
    const float* dWhh1 = dWhh + (size_t)FOURH * H1;

    if (ws_size >= NEED1) {
        // ---------------- pair path ----------------
        char* wsb = (char*)d_ws;
        __bf16* Wih0p  = (__bf16*)wsb;
        __bf16* Whh0p  = (__bf16*)(wsb + WP_SMALL);
        __bf16* Wih1p  = (__bf16*)(wsb + WP_SMALL + WP_BIG);
        __bf16* Whh1p  = (__bf16*)(wsb + WP_SMALL + 2 * WP_BIG);
        __bf16* dWih0p = (__bf16*)(wsb + WP_SMALL + 3 * WP_BIG);
        __bf16* dWhh0p = (__bf16*)(wsb + WP_SMALL + 4 * WP_BIG);
        __bf16* dWih1p = (__bf16*)(wsb + WP_SMALL + 5 * WP_BIG);
        __bf16* dWhh1p = (__bf16*)(wsb + WP_SMALL + 6 * WP_BIG);
        char* sb = wsb + WP_SMALL + 7 * WP_BIG;
        __bf16* hp0a = (__bf16*)sb;
        __bf16* hp0b = (__bf16*)(sb + HPB);
        __bf16* hp1a = (__bf16*)(sb + 2 * HPB);
        __bf16* hp1b = (__bf16*)(sb + 3 * HPB);
        float*  c0   = (float*)(sb + 4 * HPB);
        float*  c1   = c0 + CSZ;

        auto convw = [&](const float* s, __bf16* d, int K, int ks5) {
            int total = 32768 * (K >> 5);
            conv_wpair_k<<<dim3(total / 256), blk, 0, stream>>>(s, d, K, ks5);
        };
        convw(Wih0, Wih0p, 128, 2);
        convw(Whh0, Whh0p, 1024, 5);
        convw(Wih1, Wih1p, 1024, 5);
        convw(Whh1, Whh1p, 1024, 5);
        convw(dWih,  dWih0p, 1024, 5);
        convw(dWih1, dWih1p, 1024, 5);
        convw(dWhh,  dWhh0p, 1024, 5);
        convw(dWhh1, dWhh1p, 1024, 5);

        hipMemsetAsync(sb, 0, 4 * HPB + 2 * CSZ * 4, stream);

        dim3 fgrid(512);
        __bf16 *hc = hp0a, *hn = hp0b, *h1c = hp1a, *h1n = hp1b;
        const long long XROW = (long long)(SEQ * DIN * 4);
        for (int t = 0; t < SEQ; ++t) {
            lstm_fb2<<<fgrid, blk, 0, stream>>>(
                (const char*)(x + (size_t)t * DIN), XROW, DIN, 1,
                (const char*)hc, Wih0p, Whh0p, b0, c0, hn);
            lstm_fb2<<<fgrid, blk, 0, stream>>>(
                (const char*)hn, 4096LL, H1, 0,
                (const char*)h1c, Wih1p, Whh1p, b1, c1, h1n);
            __bf16* t0 = hc; hc = hn; hn = t0;
            __bf16* t1 = h1c; h1c = h1n; h1n = t1;
        }
        for (int s = 0; s < TDEC; ++s) {
            lstm_fb2<<<fgrid, blk, 0, stream>>>(
                (const char*)h1c, 4096LL, H1, 0,
                (const char*)hc, dWih0p, dWhh0p, db, c0, hn);
            lstm_fb2<<<fgrid, blk, 0, stream>>>(
                (const char*)hn, 4096LL, H1, 0,
                (const char*)h1c, dWih1p, dWhh1p, db + FOURH, c1, h1n);
            __bf16* t0 = hc; hc = hn; hn = t0;
            __bf16* t1 = h1c; h1c = h1n; h1n = t1;
        }
        head_pair2_k<<<dim3(512), blk, 0, stream>>>(h1c, Wout, bout, (float*)d_out);
    } else {
        // ---------------- f32 fallback (proven) ----------------
        float* h0a = (float*)d_ws;
        float* h0b = h0a + CSZ;
        float* h1a = h0b + CSZ;
        float* h1b = h1a + CSZ;
        float* c0  = h1b + CSZ;
        float* c1  = c0 + CSZ;
        hipMemsetAsync(h0a, 0, 6 * CSZ * 4, stream);

        (void)hipFuncSetAttribute(reinterpret_cast<const void*>(&lstm_fused_f32),
                                  hipFuncAttributeMaxDynamicSharedMemorySize, 147456);

        dim3 oldgrid(256);
        float *hc = h0a, *hn = h0b, *h1c = h1a, *h1n = h1b;
        for (int t = 0; t < SEQ; ++t) {
            lstm_fused_f32<<<oldgrid, blk, 147456, stream>>>(
                x + (size_t)t * DIN, (long long)(SEQ * DIN * 4), DIN, Wih0,
                hc, Whh0, b0, c0, hn);
            lstm_fused_f32<<<oldgrid, blk, 147456, stream>>>(
                hn, 4096LL, H1, Wih1, h1c, Whh1, b1, c1, h1n);
            float* t0 = hc; hc = hn; hn = t0;
            float* t1 = h1c; h1c = h1n; h1n = t1;
        }
        for (int s = 0; s < TDEC; ++s) {
            lstm_fused_f32<<<oldgrid, blk, 147456, stream>>>(
                h1c, 4096LL, H1, dWih, hc, dWhh, db, c0, hn);
            lstm_fused_f32<<<oldgrid, blk, 147456, stream>>>(
                hn, 4096LL, H1, dWih1, h1c, dWhh1, db + FOURH, c1, h1n);
            float* t0 = hc; hc = hn; hn = t0;
            float* t1 = h1c; h1c = h1n; h1n = t1;
        }
        head_k<<<dim3(32), blk, 0, stream>>>(h1c, Wout, bout, (float*)d_out);
    }
}